// Round 15
// baseline (816.650 us; speedup 1.0000x reference)
//
#include <hip/hip_runtime.h>
#include <hip/hip_fp16.h>

#define C_   256
#define H_   224
#define W_   224
#define HW_  (224 * 224)
#define NWH  28
#define NWW  28
#define NWIN 3136
#define NQUAD 784
#define NTILE 64
#define NFRAG (NTILE * 8 * 64)

#define XN_OFF (1ULL << 20)
#define O_OFF  (XN_OFF + (unsigned long long)NWIN * 32768ULL)
#define WS_NEED (O_OFF + (unsigned long long)NWIN * 32768ULL)   // 206.6MB, R5-proven fits

typedef _Float16 f16x8 __attribute__((ext_vector_type(8)));
typedef float    f32x4 __attribute__((ext_vector_type(4)));

// ---- byte-offset swizzles (bijective XOR; 16B-aligned) ----------------------
__device__ __forceinline__ int xn_off(int row, int col) {
  return (row * 512 + col * 2) ^ ((((row & 7) ^ ((row >> 3) & 7))) << 4);
}
__device__ __forceinline__ int qk_off(int row, int col) {
  return (row * 64 + col * 2) ^ (((row >> 1) & 3) << 4);
}
__device__ __forceinline__ int vt_off(int d, int k) {
  return (d * 128 + k * 2) ^ ((d & 7) << 4);
}
__device__ __forceinline__ int p_off(int row, int col) {
  return (row * 128 + col * 2) ^ ((row & 7) << 4);
}
__device__ __forceinline__ _Float16* xn_at(char* s, int r, int c) { return (_Float16*)(s + xn_off(r, c)); }

__device__ __forceinline__ f16x8 frag16(const _Float16* __restrict__ w16,
                                        int gt, int kk, int lane) {
  return *(const f16x8*)(w16 + ((size_t)((gt * 8 + kk) * 64 + lane)) * 8);
}

// ---- weight fp32 -> fragment-major fp16 ------------------------------------
__global__ void wcvt_kernel(const float* __restrict__ wqkv,
                            const float* __restrict__ wout,
                            _Float16* __restrict__ dst) {
  int f = blockIdx.x * blockDim.x + threadIdx.x;
  if (f >= NFRAG) return;
  int lane = f & 63, kk = (f >> 6) & 7, tile = f >> 9;
  int row = tile * 16 + (lane & 15);
  int col = kk * 32 + (lane >> 4) * 8;
  const float* src = (tile < 48) ? (wqkv + row * 256 + col)
                                 : (wout + (row - 768) * 256 + col);
  f32x4 a = *(const f32x4*)src;
  f32x4 b2 = *(const f32x4*)(src + 4);
  f16x8 r;
#pragma unroll
  for (int q = 0; q < 4; ++q) { r[q] = (_Float16)a[q]; r[q + 4] = (_Float16)b2[q]; }
  *(f16x8*)(dst + (size_t)f * 8) = r;
}

// ============================ kernel A: prep (unchanged) =====================
__global__ __launch_bounds__(512, 1) void prep_kernel(
    const float* __restrict__ x, const float* __restrict__ gamma,
    const float* __restrict__ beta, _Float16* __restrict__ xn_ws) {
  extern __shared__ char smem[];
  float* red = (float*)(smem + 131072);
  float* mrs = (float*)(smem + 147456);
  const int n0 = blockIdx.x;
  const int b  = n0 / 196;
  const int rem = n0 % 196;
  const int wh = rem / 7;
  const int wq = rem % 7;
  const int tid = threadIdx.x;
  const int px4 = (tid & 7) * 4;
  const int row = (tid >> 3) & 7;
  const int chg = tid >> 6;
  const int win = px4 >> 3;
  const int pc  = px4 & 7;
  char* xw = smem + win * 32768;

  {
    const size_t xoff = (size_t)b * C_ * HW_ + (size_t)(wh * 8 + row) * W_ + wq * 32 + px4;
    float s[4] = {0.f, 0.f, 0.f, 0.f}, q[4] = {0.f, 0.f, 0.f, 0.f};
#pragma unroll
    for (int cc = 0; cc < 32; ++cc) {
      const int ch = cc * 8 + chg;
      f32x4 v = *(const f32x4*)(x + xoff + (size_t)ch * HW_);
#pragma unroll
      for (int i = 0; i < 4; ++i) {
        *xn_at(xw, row * 8 + pc + i, ch) = (_Float16)v[i];
        s[i] += v[i]; q[i] += v[i] * v[i];
      }
    }
    const int tq = win * 64 + row * 8 + pc;
#pragma unroll
    for (int i = 0; i < 4; ++i) {
      red[(tq + i) * 8 + chg] = s[i];
      red[2048 + (tq + i) * 8 + chg] = q[i];
    }
  }
  __syncthreads();
  if (tid < 256) {
    float ss = 0.f, s2 = 0.f;
#pragma unroll
    for (int g = 0; g < 8; ++g) { ss += red[tid * 8 + g]; s2 += red[2048 + tid * 8 + g]; }
    float mu  = ss * (1.f / 256.f);
    float var = s2 * (1.f / 256.f) - mu * mu;
    mrs[tid]       = mu;
    mrs[256 + tid] = rsqrtf(var + 1e-5f);
  }
  __syncthreads();
  {
    char* dst = (char*)xn_ws + (size_t)((b * NWH + wh) * NWW + wq * 4) * 32768;
#pragma unroll
    for (int it = 0; it < 16; ++it) {
      const int a   = (it * 512 + tid) * 16;
      const int w2  = a >> 15;
      const int ab  = a & 32767;
      const int tok = ab >> 9;
      const int chb = ((ab & 511) ^ ((((tok & 7) ^ ((tok >> 3) & 7))) << 4)) >> 1;
      f16x8 hv = *(const f16x8*)(smem + a);
      const float mu = mrs[w2 * 64 + tok], rs = mrs[256 + w2 * 64 + tok];
      f32x4 g0 = *(const f32x4*)(gamma + chb), g1 = *(const f32x4*)(gamma + chb + 4);
      f32x4 b0 = *(const f32x4*)(beta + chb),  b1 = *(const f32x4*)(beta + chb + 4);
#pragma unroll
      for (int j = 0; j < 4; ++j) {
        hv[j]     = (_Float16)(((float)hv[j] - mu) * rs * g0[j] + b0[j]);
        hv[j + 4] = (_Float16)(((float)hv[j + 4] - mu) * rs * g1[j] + b1[j]);
      }
      *(f16x8*)(dst + a) = hv;
    }
  }
}

// ============================ kernel B: megattn v4 ===========================
// 256 thr = 4 waves = 2 windows; wave w -> window (w>>1), M-half (w&1).
// NO weight LDS: B-frags stream from fragment-major w16 (L2-resident, 1KB/wave
// coalesced loads). LDS = 32768 B -> 4 blocks/CU co-resident, 16 waves/CU
// = 4 waves/SIMD; blocks drift independently (no cross-block barriers).
// __launch_bounds__(256,4): 128-VGPR budget; measured live-set is 124 (R14),
// so this pins 4 waves/SIMD without forcing spills (unlike R9's 250-vs-128).
//   [0,24576)  per-window scratch winl*12288: q 4K | k 4K | vT 4K
//              (p 8KB overlays q+k after C2)
//   [24576,32768) per-window o buffer 4KB
// 3 barriers/head: D (pre-epilogue; prior head's p/vT reads done),
// C (epilogue visible cross-half), C2 (qa/kb loaded before p overlays q/k).
__global__ __launch_bounds__(256, 4) void megattn_kernel(
    const float* __restrict__ bqkv, const _Float16* __restrict__ w16,
    const _Float16* __restrict__ xn_ws, _Float16* __restrict__ o_ws) {
  extern __shared__ char smem[];
  const int tid = threadIdx.x;
  const int w = tid >> 6, lane = tid & 63, lr = lane & 15, lg = lane >> 4;
  const int winl = w >> 1;
  const int half = w & 1;
  const int r0   = half * 32;
  const int win  = blockIdx.x * 2 + winl;

  // A-fragments for this wave's M-half (64 VGPR), live across all heads
  f16x8 af[2][8];
  {
    const char* xb = (const char*)xn_ws + (size_t)win * 32768;
#pragma unroll
    for (int mi = 0; mi < 2; ++mi)
#pragma unroll
      for (int kk = 0; kk < 8; ++kk)
        af[mi][kk] = *(const f16x8*)(xb + xn_off(r0 + mi * 16 + lr, kk * 32 + lg * 8));
  }

  char* scr   = smem + winl * 12288;          // q scratch (p overlays q+k)
  char* kbase = scr + 4096;                   // k scratch
  char* vbase = scr + 8192;                   // vT
  char* obuf  = smem + 24576 + winl * 4096;   // merged o (head-local)
  char* oblob = (char*)o_ws + (size_t)win * 32768;
  const float sc_q = 0.17677669529663687f;    // 1/sqrt(32)

#pragma unroll 1
  for (int h = 0; h < 8; ++h) {
    // ---- GEMM: B-frags straight from L2; register/global only, no LDS ----
    f32x4 acc[6][2];
#pragma unroll
    for (int t = 0; t < 6; ++t)
#pragma unroll
      for (int mi = 0; mi < 2; ++mi) acc[t][mi] = (f32x4){0.f, 0.f, 0.f, 0.f};
#pragma unroll
    for (int kk = 0; kk < 8; ++kk) {
      f16x8 b0 = frag16(w16, 2 * h,      kk, lane);
      f16x8 b1 = frag16(w16, 2 * h + 1,  kk, lane);
      f16x8 b2 = frag16(w16, 16 + 2 * h, kk, lane);
      f16x8 b3 = frag16(w16, 17 + 2 * h, kk, lane);
      f16x8 b4 = frag16(w16, 32 + 2 * h, kk, lane);
      f16x8 b5 = frag16(w16, 33 + 2 * h, kk, lane);
#pragma unroll
      for (int mi = 0; mi < 2; ++mi) {
        acc[0][mi] = __builtin_amdgcn_mfma_f32_16x16x32_f16(af[mi][kk], b0, acc[0][mi], 0, 0, 0);
        acc[1][mi] = __builtin_amdgcn_mfma_f32_16x16x32_f16(af[mi][kk], b1, acc[1][mi], 0, 0, 0);
        acc[2][mi] = __builtin_amdgcn_mfma_f32_16x16x32_f16(af[mi][kk], b2, acc[2][mi], 0, 0, 0);
        acc[3][mi] = __builtin_amdgcn_mfma_f32_16x16x32_f16(af[mi][kk], b3, acc[3][mi], 0, 0, 0);
        acc[4][mi] = __builtin_amdgcn_mfma_f32_16x16x32_f16(af[mi][kk], b4, acc[4][mi], 0, 0, 0);
        acc[5][mi] = __builtin_amdgcn_mfma_f32_16x16x32_f16(af[mi][kk], b5, acc[5][mi], 0, 0, 0);
      }
    }
    __syncthreads();   // D: prior head's p/vT reads complete before overwrite

    // ---- epilogue: q scaled+bias, k bias, vT (this wave's token half) ----
#pragma unroll
    for (int t2 = 0; t2 < 2; ++t2) {
      const float bq = bqkv[h * 32 + t2 * 16 + lr];
      const float bk = bqkv[256 + h * 32 + t2 * 16 + lr];
      const float bv = bqkv[512 + h * 32 + t2 * 16 + lr];
#pragma unroll
      for (int mi = 0; mi < 2; ++mi)
#pragma unroll
        for (int i = 0; i < 4; ++i) {
          const int trow = r0 + mi * 16 + lg * 4 + i;
          *(_Float16*)(scr + qk_off(trow, t2 * 16 + lr))   = (_Float16)((acc[t2][mi][i] + bq) * sc_q);
          *(_Float16*)(kbase + qk_off(trow, t2 * 16 + lr)) = (_Float16)(acc[2 + t2][mi][i] + bk);
          *(_Float16*)(vbase + vt_off(t2 * 16 + lr, trow)) = (_Float16)(acc[4 + t2][mi][i] + bv);
        }
    }
    __syncthreads();   // C: both halves' q/k/vT visible

    // ---- scores: own q rows x ALL k rows ----
    f16x8 qa[2], kb[4];
#pragma unroll
    for (int mi = 0; mi < 2; ++mi)
      qa[mi] = *(const f16x8*)(scr + qk_off(r0 + mi * 16 + lr, lg * 8));
#pragma unroll
    for (int ni = 0; ni < 4; ++ni)
      kb[ni] = *(const f16x8*)(kbase + qk_off(ni * 16 + lr, lg * 8));
    __syncthreads();   // C2: all waves' qa/kb loaded before p overlays q/k

    float oinv[2][4];
#pragma unroll
    for (int mi = 0; mi < 2; ++mi) {
      f32x4 s4[4];
#pragma unroll
      for (int ni = 0; ni < 4; ++ni) {
        f32x4 z = {0.f, 0.f, 0.f, 0.f};
        s4[ni] = __builtin_amdgcn_mfma_f32_16x16x32_f16(qa[mi], kb[ni], z, 0, 0, 0);
      }
#pragma unroll
      for (int i = 0; i < 4; ++i) {
        float m = fmaxf(fmaxf(s4[0][i], s4[1][i]), fmaxf(s4[2][i], s4[3][i]));
        m = fmaxf(m, __shfl_xor(m, 1));
        m = fmaxf(m, __shfl_xor(m, 2));
        m = fmaxf(m, __shfl_xor(m, 4));
        m = fmaxf(m, __shfl_xor(m, 8));
        float s = 0.f;
#pragma unroll
        for (int ni = 0; ni < 4; ++ni) {
          float e = __expf(s4[ni][i] - m);
          s4[ni][i] = e;
          s += e;
        }
        s += __shfl_xor(s, 1);
        s += __shfl_xor(s, 2);
        s += __shfl_xor(s, 4);
        s += __shfl_xor(s, 8);
        oinv[mi][i] = 1.f / s;
      }
#pragma unroll
      for (int ni = 0; ni < 4; ++ni)
#pragma unroll
        for (int i = 0; i < 4; ++i)
          *(_Float16*)(scr + p_off(r0 + mi * 16 + lg * 4 + i, ni * 16 + lr)) = (_Float16)s4[ni][i];
    }
    // ---- PV: own p rows x all vT ----
    f32x4 oacc[2][2];
#pragma unroll
    for (int mi = 0; mi < 2; ++mi)
#pragma unroll
      for (int nt2 = 0; nt2 < 2; ++nt2) oacc[mi][nt2] = (f32x4){0.f, 0.f, 0.f, 0.f};
#pragma unroll
    for (int ks2 = 0; ks2 < 2; ++ks2) {
      f16x8 pa[2];
#pragma unroll
      for (int mi = 0; mi < 2; ++mi)
        pa[mi] = *(const f16x8*)(scr + p_off(r0 + mi * 16 + lr, ks2 * 32 + lg * 8));
#pragma unroll
      for (int nt2 = 0; nt2 < 2; ++nt2) {
        f16x8 vb = *(const f16x8*)(vbase + vt_off(nt2 * 16 + lr, ks2 * 32 + lg * 8));
#pragma unroll
        for (int mi = 0; mi < 2; ++mi)
          oacc[mi][nt2] = __builtin_amdgcn_mfma_f32_16x16x32_f16(pa[mi], vb, oacc[mi][nt2], 0, 0, 0);
      }
    }
    // ---- o-head: assemble own rows in obuf, dump own 2KB half ----
#pragma unroll
    for (int mi = 0; mi < 2; ++mi)
#pragma unroll
      for (int nt2 = 0; nt2 < 2; ++nt2)
#pragma unroll
        for (int i = 0; i < 4; ++i)
          *(_Float16*)(obuf + qk_off(r0 + mi * 16 + lg * 4 + i, nt2 * 16 + lr)) =
              (_Float16)(oacc[mi][nt2][i] * oinv[mi][i]);
#pragma unroll
    for (int j = 0; j < 2; ++j)
      *(f32x4*)(oblob + h * 4096 + half * 2048 + lane * 32 + j * 16) =
          *(const f32x4*)(obuf + half * 2048 + lane * 32 + j * 16);
  }
}

// ============================ kernel C: out-proj (unchanged) =================
__global__ __launch_bounds__(512, 1) void outproj_kernel(
    const _Float16* __restrict__ o_ws, const _Float16* __restrict__ w16,
    const float* __restrict__ bout, float* __restrict__ out) {
  extern __shared__ char smem[];
  const int n0 = blockIdx.x;
  const int b  = n0 / 196;
  const int rem = n0 % 196;
  const int wh = rem / 7;
  const int wq = rem % 7;
  const int tid = threadIdx.x;
  const int w = tid >> 6, lane = tid & 63, lr = lane & 15, lg = lane >> 4;

  {
    const char* src = (const char*)o_ws + (size_t)((b * NWH + wh) * NWW + wq * 4) * 32768;
#pragma unroll
    for (int it = 0; it < 16; ++it) {
      const int off = (it * 512 + tid) * 16;
      *(f32x4*)(smem + off) = *(const f32x4*)(src + off);
    }
  }
  __syncthreads();

  f32x4 acc[4][2][4];
#pragma unroll
  for (int wi = 0; wi < 4; ++wi)
#pragma unroll
    for (int t = 0; t < 2; ++t)
#pragma unroll
      for (int mi = 0; mi < 4; ++mi) acc[wi][t][mi] = (f32x4){0.f, 0.f, 0.f, 0.f};

#pragma unroll
  for (int kk = 0; kk < 8; ++kk) {   // kk == head of the o blob
    f16x8 bf0 = frag16(w16, 48 + w * 2 + 0, kk, lane);
    f16x8 bf1 = frag16(w16, 48 + w * 2 + 1, kk, lane);
#pragma unroll
    for (int wi = 0; wi < 4; ++wi) {
      f16x8 af[4];
#pragma unroll
      for (int mi = 0; mi < 4; ++mi)
        af[mi] = *(const f16x8*)(smem + wi * 32768 + kk * 4096 + qk_off(mi * 16 + lr, lg * 8));
#pragma unroll
      for (int mi = 0; mi < 4; ++mi) {
        acc[wi][0][mi] = __builtin_amdgcn_mfma_f32_16x16x32_f16(af[mi], bf0, acc[wi][0][mi], 0, 0, 0);
        acc[wi][1][mi] = __builtin_amdgcn_mfma_f32_16x16x32_f16(af[mi], bf1, acc[wi][1][mi], 0, 0, 0);
      }
    }
  }

#pragma unroll
  for (int ntl = 0; ntl < 2; ++ntl) {
    const int och = w * 32 + ntl * 16 + lr;
    const float bias = bout[och];
    float* ob = out + ((size_t)(b * C_ + och) * H_ + wh * 8) * W_ + wq * 32;
#pragma unroll
    for (int mi = 0; mi < 4; ++mi) {
      const int tb = mi * 16 + lg * 4;
      const int ro = (tb >> 3) * W_ + (tb & 7);
#pragma unroll
      for (int wi = 0; wi < 4; ++wi) {
        f32x4 ov;
#pragma unroll
        for (int i = 0; i < 4; ++i) ov[i] = acc[wi][ntl][mi][i] + bias;
        *(f32x4*)&ob[ro + wi * 8] = ov;
      }
    }
  }
}

extern "C" void kernel_launch(void* const* d_in, const int* in_sizes, int n_in,
                              void* d_out, int out_size, void* d_ws, size_t ws_size,
                              hipStream_t stream) {
  (void)in_sizes; (void)n_in; (void)out_size; (void)ws_size;
  const float* x     = (const float*)d_in[0];
  const float* gamma = (const float*)d_in[1];
  const float* beta  = (const float*)d_in[2];
  const float* wqkv  = (const float*)d_in[3];
  const float* bqkv  = (const float*)d_in[4];
  const float* wout  = (const float*)d_in[5];
  const float* bout  = (const float*)d_in[6];
  float* out = (float*)d_out;

  _Float16* w16   = (_Float16*)d_ws;
  _Float16* xn_ws = (_Float16*)((char*)d_ws + XN_OFF);
  _Float16* o_ws  = (_Float16*)((char*)d_ws + O_OFF);

  static int attr_set = 0;
  if (!attr_set) {
    (void)hipFuncSetAttribute((const void*)prep_kernel,
                              hipFuncAttributeMaxDynamicSharedMemorySize, 149504);
    (void)hipFuncSetAttribute((const void*)megattn_kernel,
                              hipFuncAttributeMaxDynamicSharedMemorySize, 32768);
    (void)hipFuncSetAttribute((const void*)outproj_kernel,
                              hipFuncAttributeMaxDynamicSharedMemorySize, 131072);
    attr_set = 1;
  }

  wcvt_kernel<<<NFRAG / 256, 256, 0, stream>>>(wqkv, wout, w16);
  prep_kernel<<<NQUAD, 512, 149504, stream>>>(x, gamma, beta, xn_ws);
  megattn_kernel<<<NWIN / 2, 256, 32768, stream>>>(bqkv, w16, xn_ws, o_ws);
  outproj_kernel<<<NQUAD, 512, 131072, stream>>>(o_ws, w16, bout, out);
}

// Round 16
// 621.488 us; speedup vs baseline: 1.3140x; 1.3140x over previous
//
#include <hip/hip_runtime.h>
#include <hip/hip_fp16.h>

#define C_   256
#define H_   224
#define W_   224
#define HW_  (224 * 224)
#define NWH  28
#define NWW  28
#define NWIN 3136
#define NQUAD 784
#define NTILE 64
#define NFRAG (NTILE * 8 * 64)

#define XN_OFF (1ULL << 20)
#define O_OFF  (XN_OFF + (unsigned long long)NWIN * 32768ULL)
#define WS_NEED (O_OFF + (unsigned long long)NWIN * 32768ULL)   // 206.6MB, R5-proven fits

typedef _Float16 f16x8 __attribute__((ext_vector_type(8)));
typedef float    f32x4 __attribute__((ext_vector_type(4)));

// ---- byte-offset swizzles (bijective XOR; 16B-aligned) ----------------------
__device__ __forceinline__ int xn_off(int row, int col) {
  return (row * 512 + col * 2) ^ ((((row & 7) ^ ((row >> 3) & 7))) << 4);
}
__device__ __forceinline__ int qk_off(int row, int col) {
  return (row * 64 + col * 2) ^ (((row >> 1) & 3) << 4);
}
__device__ __forceinline__ int vt_off(int d, int k) {
  return (d * 128 + k * 2) ^ ((d & 7) << 4);
}
__device__ __forceinline__ int p_off(int row, int col) {
  return (row * 128 + col * 2) ^ ((row & 7) << 4);
}
__device__ __forceinline__ _Float16* xn_at(char* s, int r, int c) { return (_Float16*)(s + xn_off(r, c)); }

__device__ __forceinline__ f16x8 frag16(const _Float16* __restrict__ w16,
                                        int gt, int kk, int lane) {
  return *(const f16x8*)(w16 + ((size_t)((gt * 8 + kk) * 64 + lane)) * 8);
}

// ---- weight fp32 -> fragment-major fp16 ------------------------------------
__global__ void wcvt_kernel(const float* __restrict__ wqkv,
                            const float* __restrict__ wout,
                            _Float16* __restrict__ dst) {
  int f = blockIdx.x * blockDim.x + threadIdx.x;
  if (f >= NFRAG) return;
  int lane = f & 63, kk = (f >> 6) & 7, tile = f >> 9;
  int row = tile * 16 + (lane & 15);
  int col = kk * 32 + (lane >> 4) * 8;
  const float* src = (tile < 48) ? (wqkv + row * 256 + col)
                                 : (wout + (row - 768) * 256 + col);
  f32x4 a = *(const f32x4*)src;
  f32x4 b2 = *(const f32x4*)(src + 4);
  f16x8 r;
#pragma unroll
  for (int q = 0; q < 4; ++q) { r[q] = (_Float16)a[q]; r[q + 4] = (_Float16)b2[q]; }
  *(f16x8*)(dst + (size_t)f * 8) = r;
}

// ============================ kernel A: prep (unchanged) =====================
__global__ __launch_bounds__(512, 1) void prep_kernel(
    const float* __restrict__ x, const float* __restrict__ gamma,
    const float* __restrict__ beta, _Float16* __restrict__ xn_ws) {
  extern __shared__ char smem[];
  float* red = (float*)(smem + 131072);
  float* mrs = (float*)(smem + 147456);
  const int n0 = blockIdx.x;
  const int b  = n0 / 196;
  const int rem = n0 % 196;
  const int wh = rem / 7;
  const int wq = rem % 7;
  const int tid = threadIdx.x;
  const int px4 = (tid & 7) * 4;
  const int row = (tid >> 3) & 7;
  const int chg = tid >> 6;
  const int win = px4 >> 3;
  const int pc  = px4 & 7;
  char* xw = smem + win * 32768;

  {
    const size_t xoff = (size_t)b * C_ * HW_ + (size_t)(wh * 8 + row) * W_ + wq * 32 + px4;
    float s[4] = {0.f, 0.f, 0.f, 0.f}, q[4] = {0.f, 0.f, 0.f, 0.f};
#pragma unroll
    for (int cc = 0; cc < 32; ++cc) {
      const int ch = cc * 8 + chg;
      f32x4 v = *(const f32x4*)(x + xoff + (size_t)ch * HW_);
#pragma unroll
      for (int i = 0; i < 4; ++i) {
        *xn_at(xw, row * 8 + pc + i, ch) = (_Float16)v[i];
        s[i] += v[i]; q[i] += v[i] * v[i];
      }
    }
    const int tq = win * 64 + row * 8 + pc;
#pragma unroll
    for (int i = 0; i < 4; ++i) {
      red[(tq + i) * 8 + chg] = s[i];
      red[2048 + (tq + i) * 8 + chg] = q[i];
    }
  }
  __syncthreads();
  if (tid < 256) {
    float ss = 0.f, s2 = 0.f;
#pragma unroll
    for (int g = 0; g < 8; ++g) { ss += red[tid * 8 + g]; s2 += red[2048 + tid * 8 + g]; }
    float mu  = ss * (1.f / 256.f);
    float var = s2 * (1.f / 256.f) - mu * mu;
    mrs[tid]       = mu;
    mrs[256 + tid] = rsqrtf(var + 1e-5f);
  }
  __syncthreads();
  {
    char* dst = (char*)xn_ws + (size_t)((b * NWH + wh) * NWW + wq * 4) * 32768;
#pragma unroll
    for (int it = 0; it < 16; ++it) {
      const int a   = (it * 512 + tid) * 16;
      const int w2  = a >> 15;
      const int ab  = a & 32767;
      const int tok = ab >> 9;
      const int chb = ((ab & 511) ^ ((((tok & 7) ^ ((tok >> 3) & 7))) << 4)) >> 1;
      f16x8 hv = *(const f16x8*)(smem + a);
      const float mu = mrs[w2 * 64 + tok], rs = mrs[256 + w2 * 64 + tok];
      f32x4 g0 = *(const f32x4*)(gamma + chb), g1 = *(const f32x4*)(gamma + chb + 4);
      f32x4 b0 = *(const f32x4*)(beta + chb),  b1 = *(const f32x4*)(beta + chb + 4);
#pragma unroll
      for (int j = 0; j < 4; ++j) {
        hv[j]     = (_Float16)(((float)hv[j] - mu) * rs * g0[j] + b0[j]);
        hv[j + 4] = (_Float16)(((float)hv[j + 4] - mu) * rs * g1[j] + b1[j]);
      }
      *(f16x8*)(dst + a) = hv;
    }
  }
}

// ============================ kernel B: megattn v4b ==========================
// 256 thr = 4 waves = 2 windows; wave w -> window (w>>1), M-half (w&1).
// NO weight LDS: B-frags stream from fragment-major w16 (L2-resident, 1KB/wave
// coalesced loads). LDS = 32768 B -> up to 4 blocks/CU co-resident if natural
// VGPR <= 128 (R14's near-identical inner code measured 124).
// __launch_bounds__(256,1): NATURAL register allocation. R15 proved (256,4)
// coerces a 64-VGPR budget and spills everything (FETCH 55->813MB, 641us);
// R9 proved (256,2) the same at 128. NEVER pass min-waves > 1 here.
//   [0,24576)  per-window scratch winl*12288: q 4K | k 4K | vT 4K
//              (p 8KB overlays q+k after C2)
//   [24576,32768) per-window o buffer 4KB
// 3 barriers/head: D (pre-epilogue; prior head's p/vT reads done),
// C (epilogue visible cross-half), C2 (qa/kb loaded before p overlays q/k).
__global__ __launch_bounds__(256, 1) void megattn_kernel(
    const float* __restrict__ bqkv, const _Float16* __restrict__ w16,
    const _Float16* __restrict__ xn_ws, _Float16* __restrict__ o_ws) {
  extern __shared__ char smem[];
  const int tid = threadIdx.x;
  const int w = tid >> 6, lane = tid & 63, lr = lane & 15, lg = lane >> 4;
  const int winl = w >> 1;
  const int half = w & 1;
  const int r0   = half * 32;
  const int win  = blockIdx.x * 2 + winl;

  // A-fragments for this wave's M-half (32 VGPR), live across all heads
  f16x8 af[2][8];
  {
    const char* xb = (const char*)xn_ws + (size_t)win * 32768;
#pragma unroll
    for (int mi = 0; mi < 2; ++mi)
#pragma unroll
      for (int kk = 0; kk < 8; ++kk)
        af[mi][kk] = *(const f16x8*)(xb + xn_off(r0 + mi * 16 + lr, kk * 32 + lg * 8));
  }

  char* scr   = smem + winl * 12288;          // q scratch (p overlays q+k)
  char* kbase = scr + 4096;                   // k scratch
  char* vbase = scr + 8192;                   // vT
  char* obuf  = smem + 24576 + winl * 4096;   // merged o (head-local)
  char* oblob = (char*)o_ws + (size_t)win * 32768;
  const float sc_q = 0.17677669529663687f;    // 1/sqrt(32)

#pragma unroll 1
  for (int h = 0; h < 8; ++h) {
    // ---- GEMM: B-frags straight from L2; register/global only, no LDS ----
    f32x4 acc[6][2];
#pragma unroll
    for (int t = 0; t < 6; ++t)
#pragma unroll
      for (int mi = 0; mi < 2; ++mi) acc[t][mi] = (f32x4){0.f, 0.f, 0.f, 0.f};
#pragma unroll
    for (int kk = 0; kk < 8; ++kk) {
      f16x8 b0 = frag16(w16, 2 * h,      kk, lane);
      f16x8 b1 = frag16(w16, 2 * h + 1,  kk, lane);
      f16x8 b2 = frag16(w16, 16 + 2 * h, kk, lane);
      f16x8 b3 = frag16(w16, 17 + 2 * h, kk, lane);
      f16x8 b4 = frag16(w16, 32 + 2 * h, kk, lane);
      f16x8 b5 = frag16(w16, 33 + 2 * h, kk, lane);
#pragma unroll
      for (int mi = 0; mi < 2; ++mi) {
        acc[0][mi] = __builtin_amdgcn_mfma_f32_16x16x32_f16(af[mi][kk], b0, acc[0][mi], 0, 0, 0);
        acc[1][mi] = __builtin_amdgcn_mfma_f32_16x16x32_f16(af[mi][kk], b1, acc[1][mi], 0, 0, 0);
        acc[2][mi] = __builtin_amdgcn_mfma_f32_16x16x32_f16(af[mi][kk], b2, acc[2][mi], 0, 0, 0);
        acc[3][mi] = __builtin_amdgcn_mfma_f32_16x16x32_f16(af[mi][kk], b3, acc[3][mi], 0, 0, 0);
        acc[4][mi] = __builtin_amdgcn_mfma_f32_16x16x32_f16(af[mi][kk], b4, acc[4][mi], 0, 0, 0);
        acc[5][mi] = __builtin_amdgcn_mfma_f32_16x16x32_f16(af[mi][kk], b5, acc[5][mi], 0, 0, 0);
      }
    }
    __syncthreads();   // D: prior head's p/vT reads complete before overwrite

    // ---- epilogue: q scaled+bias, k bias, vT (this wave's token half) ----
#pragma unroll
    for (int t2 = 0; t2 < 2; ++t2) {
      const float bq = bqkv[h * 32 + t2 * 16 + lr];
      const float bk = bqkv[256 + h * 32 + t2 * 16 + lr];
      const float bv = bqkv[512 + h * 32 + t2 * 16 + lr];
#pragma unroll
      for (int mi = 0; mi < 2; ++mi)
#pragma unroll
        for (int i = 0; i < 4; ++i) {
          const int trow = r0 + mi * 16 + lg * 4 + i;
          *(_Float16*)(scr + qk_off(trow, t2 * 16 + lr))   = (_Float16)((acc[t2][mi][i] + bq) * sc_q);
          *(_Float16*)(kbase + qk_off(trow, t2 * 16 + lr)) = (_Float16)(acc[2 + t2][mi][i] + bk);
          *(_Float16*)(vbase + vt_off(t2 * 16 + lr, trow)) = (_Float16)(acc[4 + t2][mi][i] + bv);
        }
    }
    __syncthreads();   // C: both halves' q/k/vT visible

    // ---- scores: own q rows x ALL k rows ----
    f16x8 qa[2], kb[4];
#pragma unroll
    for (int mi = 0; mi < 2; ++mi)
      qa[mi] = *(const f16x8*)(scr + qk_off(r0 + mi * 16 + lr, lg * 8));
#pragma unroll
    for (int ni = 0; ni < 4; ++ni)
      kb[ni] = *(const f16x8*)(kbase + qk_off(ni * 16 + lr, lg * 8));
    __syncthreads();   // C2: all waves' qa/kb loaded before p overlays q/k

    float oinv[2][4];
#pragma unroll
    for (int mi = 0; mi < 2; ++mi) {
      f32x4 s4[4];
#pragma unroll
      for (int ni = 0; ni < 4; ++ni) {
        f32x4 z = {0.f, 0.f, 0.f, 0.f};
        s4[ni] = __builtin_amdgcn_mfma_f32_16x16x32_f16(qa[mi], kb[ni], z, 0, 0, 0);
      }
#pragma unroll
      for (int i = 0; i < 4; ++i) {
        float m = fmaxf(fmaxf(s4[0][i], s4[1][i]), fmaxf(s4[2][i], s4[3][i]));
        m = fmaxf(m, __shfl_xor(m, 1));
        m = fmaxf(m, __shfl_xor(m, 2));
        m = fmaxf(m, __shfl_xor(m, 4));
        m = fmaxf(m, __shfl_xor(m, 8));
        float s = 0.f;
#pragma unroll
        for (int ni = 0; ni < 4; ++ni) {
          float e = __expf(s4[ni][i] - m);
          s4[ni][i] = e;
          s += e;
        }
        s += __shfl_xor(s, 1);
        s += __shfl_xor(s, 2);
        s += __shfl_xor(s, 4);
        s += __shfl_xor(s, 8);
        oinv[mi][i] = 1.f / s;
      }
#pragma unroll
      for (int ni = 0; ni < 4; ++ni)
#pragma unroll
        for (int i = 0; i < 4; ++i)
          *(_Float16*)(scr + p_off(r0 + mi * 16 + lg * 4 + i, ni * 16 + lr)) = (_Float16)s4[ni][i];
    }
    // ---- PV: own p rows x all vT ----
    f32x4 oacc[2][2];
#pragma unroll
    for (int mi = 0; mi < 2; ++mi)
#pragma unroll
      for (int nt2 = 0; nt2 < 2; ++nt2) oacc[mi][nt2] = (f32x4){0.f, 0.f, 0.f, 0.f};
#pragma unroll
    for (int ks2 = 0; ks2 < 2; ++ks2) {
      f16x8 pa[2];
#pragma unroll
      for (int mi = 0; mi < 2; ++mi)
        pa[mi] = *(const f16x8*)(scr + p_off(r0 + mi * 16 + lr, ks2 * 32 + lg * 8));
#pragma unroll
      for (int nt2 = 0; nt2 < 2; ++nt2) {
        f16x8 vb = *(const f16x8*)(vbase + vt_off(nt2 * 16 + lr, ks2 * 32 + lg * 8));
#pragma unroll
        for (int mi = 0; mi < 2; ++mi)
          oacc[mi][nt2] = __builtin_amdgcn_mfma_f32_16x16x32_f16(pa[mi], vb, oacc[mi][nt2], 0, 0, 0);
      }
    }
    // ---- o-head: assemble own rows in obuf, dump own 2KB half ----
#pragma unroll
    for (int mi = 0; mi < 2; ++mi)
#pragma unroll
      for (int nt2 = 0; nt2 < 2; ++nt2)
#pragma unroll
        for (int i = 0; i < 4; ++i)
          *(_Float16*)(obuf + qk_off(r0 + mi * 16 + lg * 4 + i, nt2 * 16 + lr)) =
              (_Float16)(oacc[mi][nt2][i] * oinv[mi][i]);
#pragma unroll
    for (int j = 0; j < 2; ++j)
      *(f32x4*)(oblob + h * 4096 + half * 2048 + lane * 32 + j * 16) =
          *(const f32x4*)(obuf + half * 2048 + lane * 32 + j * 16);
  }
}

// ============================ kernel C: out-proj (unchanged) =================
__global__ __launch_bounds__(512, 1) void outproj_kernel(
    const _Float16* __restrict__ o_ws, const _Float16* __restrict__ w16,
    const float* __restrict__ bout, float* __restrict__ out) {
  extern __shared__ char smem[];
  const int n0 = blockIdx.x;
  const int b  = n0 / 196;
  const int rem = n0 % 196;
  const int wh = rem / 7;
  const int wq = rem % 7;
  const int tid = threadIdx.x;
  const int w = tid >> 6, lane = tid & 63, lr = lane & 15, lg = lane >> 4;

  {
    const char* src = (const char*)o_ws + (size_t)((b * NWH + wh) * NWW + wq * 4) * 32768;
#pragma unroll
    for (int it = 0; it < 16; ++it) {
      const int off = (it * 512 + tid) * 16;
      *(f32x4*)(smem + off) = *(const f32x4*)(src + off);
    }
  }
  __syncthreads();

  f32x4 acc[4][2][4];
#pragma unroll
  for (int wi = 0; wi < 4; ++wi)
#pragma unroll
    for (int t = 0; t < 2; ++t)
#pragma unroll
      for (int mi = 0; mi < 4; ++mi) acc[wi][t][mi] = (f32x4){0.f, 0.f, 0.f, 0.f};

#pragma unroll
  for (int kk = 0; kk < 8; ++kk) {   // kk == head of the o blob
    f16x8 bf0 = frag16(w16, 48 + w * 2 + 0, kk, lane);
    f16x8 bf1 = frag16(w16, 48 + w * 2 + 1, kk, lane);
#pragma unroll
    for (int wi = 0; wi < 4; ++wi) {
      f16x8 af[4];
#pragma unroll
      for (int mi = 0; mi < 4; ++mi)
        af[mi] = *(const f16x8*)(smem + wi * 32768 + kk * 4096 + qk_off(mi * 16 + lr, lg * 8));
#pragma unroll
      for (int mi = 0; mi < 4; ++mi) {
        acc[wi][0][mi] = __builtin_amdgcn_mfma_f32_16x16x32_f16(af[mi], bf0, acc[wi][0][mi], 0, 0, 0);
        acc[wi][1][mi] = __builtin_amdgcn_mfma_f32_16x16x32_f16(af[mi], bf1, acc[wi][1][mi], 0, 0, 0);
      }
    }
  }

#pragma unroll
  for (int ntl = 0; ntl < 2; ++ntl) {
    const int och = w * 32 + ntl * 16 + lr;
    const float bias = bout[och];
    float* ob = out + ((size_t)(b * C_ + och) * H_ + wh * 8) * W_ + wq * 32;
#pragma unroll
    for (int mi = 0; mi < 4; ++mi) {
      const int tb = mi * 16 + lg * 4;
      const int ro = (tb >> 3) * W_ + (tb & 7);
#pragma unroll
      for (int wi = 0; wi < 4; ++wi) {
        f32x4 ov;
#pragma unroll
        for (int i = 0; i < 4; ++i) ov[i] = acc[wi][ntl][mi][i] + bias;
        *(f32x4*)&ob[ro + wi * 8] = ov;
      }
    }
  }
}

extern "C" void kernel_launch(void* const* d_in, const int* in_sizes, int n_in,
                              void* d_out, int out_size, void* d_ws, size_t ws_size,
                              hipStream_t stream) {
  (void)in_sizes; (void)n_in; (void)out_size; (void)ws_size;
  const float* x     = (const float*)d_in[0];
  const float* gamma = (const float*)d_in[1];
  const float* beta  = (const float*)d_in[2];
  const float* wqkv  = (const float*)d_in[3];
  const float* bqkv  = (const float*)d_in[4];
  const float* wout  = (const float*)d_in[5];
  const float* bout  = (const float*)d_in[6];
  float* out = (float*)d_out;

  _Float16* w16   = (_Float16*)d_ws;
  _Float16* xn_ws = (_Float16*)((char*)d_ws + XN_OFF);
  _Float16* o_ws  = (_Float16*)((char*)d_ws + O_OFF);

  static int attr_set = 0;
  if (!attr_set) {
    (void)hipFuncSetAttribute((const void*)prep_kernel,
                              hipFuncAttributeMaxDynamicSharedMemorySize, 149504);
    (void)hipFuncSetAttribute((const void*)megattn_kernel,
                              hipFuncAttributeMaxDynamicSharedMemorySize, 32768);
    (void)hipFuncSetAttribute((const void*)outproj_kernel,
                              hipFuncAttributeMaxDynamicSharedMemorySize, 131072);
    attr_set = 1;
  }

  wcvt_kernel<<<NFRAG / 256, 256, 0, stream>>>(wqkv, wout, w16);
  prep_kernel<<<NQUAD, 512, 149504, stream>>>(x, gamma, beta, xn_ws);
  megattn_kernel<<<NWIN / 2, 256, 32768, stream>>>(bqkv, w16, xn_ws, o_ws);
  outproj_kernel<<<NQUAD, 512, 131072, stream>>>(o_ws, w16, bout, out);
}

// Round 17
// 533.744 us; speedup vs baseline: 1.5300x; 1.1644x over previous
//
#include <hip/hip_runtime.h>
#include <hip/hip_fp16.h>

#define C_   256
#define H_   224
#define W_   224
#define HW_  (224 * 224)
#define NWH  28
#define NWW  28
#define NWIN 3136
#define NQUAD 784
#define NTILE 64
#define NFRAG (NTILE * 8 * 64)

#define XN_OFF (1ULL << 20)
#define O_OFF  (XN_OFF + (unsigned long long)NWIN * 32768ULL)
#define WS_NEED (O_OFF + (unsigned long long)NWIN * 32768ULL)   // 206.6MB, R5-proven fits

typedef _Float16 f16x8 __attribute__((ext_vector_type(8)));
typedef float    f32x4 __attribute__((ext_vector_type(4)));

// ---- byte-offset swizzles (bijective XOR; 16B-aligned) ----------------------
__device__ __forceinline__ int xn_off(int row, int col) {
  return (row * 512 + col * 2) ^ ((((row & 7) ^ ((row >> 3) & 7))) << 4);
}
__device__ __forceinline__ int qk_off(int row, int col) {
  return (row * 64 + col * 2) ^ (((row >> 1) & 3) << 4);
}
__device__ __forceinline__ int vt_off(int d, int k) {
  return (d * 128 + k * 2) ^ ((d & 7) << 4);
}
__device__ __forceinline__ int p_off(int row, int col) {
  return (row * 128 + col * 2) ^ ((row & 7) << 4);
}
__device__ __forceinline__ _Float16* xn_at(char* s, int r, int c) { return (_Float16*)(s + xn_off(r, c)); }

__device__ __forceinline__ f16x8 frag16(const _Float16* __restrict__ w16,
                                        int gt, int kk, int lane) {
  return *(const f16x8*)(w16 + ((size_t)((gt * 8 + kk) * 64 + lane)) * 8);
}

// weight prefetch source: head h, 1KB-chunk c (0..47), lane
__device__ __forceinline__ const char* wsrc(const char* w16b, int h, int c, int lane) {
  const int reg = c >> 4;               // 0=q 1=k 2=v region
  const int off = (c & 15) << 10;       // byte offset within region
  return w16b + (size_t)(reg * 16 + 2 * h) * 8192 + off + lane * 16;
}

// ---- weight fp32 -> fragment-major fp16 ------------------------------------
__global__ void wcvt_kernel(const float* __restrict__ wqkv,
                            const float* __restrict__ wout,
                            _Float16* __restrict__ dst) {
  int f = blockIdx.x * blockDim.x + threadIdx.x;
  if (f >= NFRAG) return;
  int lane = f & 63, kk = (f >> 6) & 7, tile = f >> 9;
  int row = tile * 16 + (lane & 15);
  int col = kk * 32 + (lane >> 4) * 8;
  const float* src = (tile < 48) ? (wqkv + row * 256 + col)
                                 : (wout + (row - 768) * 256 + col);
  f32x4 a = *(const f32x4*)src;
  f32x4 b2 = *(const f32x4*)(src + 4);
  f16x8 r;
#pragma unroll
  for (int q = 0; q < 4; ++q) { r[q] = (_Float16)a[q]; r[q + 4] = (_Float16)b2[q]; }
  *(f16x8*)(dst + (size_t)f * 8) = r;
}

// ============================ kernel A: prep (unchanged) =====================
__global__ __launch_bounds__(512, 1) void prep_kernel(
    const float* __restrict__ x, const float* __restrict__ gamma,
    const float* __restrict__ beta, _Float16* __restrict__ xn_ws) {
  extern __shared__ char smem[];
  float* red = (float*)(smem + 131072);
  float* mrs = (float*)(smem + 147456);
  const int n0 = blockIdx.x;
  const int b  = n0 / 196;
  const int rem = n0 % 196;
  const int wh = rem / 7;
  const int wq = rem % 7;
  const int tid = threadIdx.x;
  const int px4 = (tid & 7) * 4;
  const int row = (tid >> 3) & 7;
  const int chg = tid >> 6;
  const int win = px4 >> 3;
  const int pc  = px4 & 7;
  char* xw = smem + win * 32768;

  {
    const size_t xoff = (size_t)b * C_ * HW_ + (size_t)(wh * 8 + row) * W_ + wq * 32 + px4;
    float s[4] = {0.f, 0.f, 0.f, 0.f}, q[4] = {0.f, 0.f, 0.f, 0.f};
#pragma unroll
    for (int cc = 0; cc < 32; ++cc) {
      const int ch = cc * 8 + chg;
      f32x4 v = *(const f32x4*)(x + xoff + (size_t)ch * HW_);
#pragma unroll
      for (int i = 0; i < 4; ++i) {
        *xn_at(xw, row * 8 + pc + i, ch) = (_Float16)v[i];
        s[i] += v[i]; q[i] += v[i] * v[i];
      }
    }
    const int tq = win * 64 + row * 8 + pc;
#pragma unroll
    for (int i = 0; i < 4; ++i) {
      red[(tq + i) * 8 + chg] = s[i];
      red[2048 + (tq + i) * 8 + chg] = q[i];
    }
  }
  __syncthreads();
  if (tid < 256) {
    float ss = 0.f, s2 = 0.f;
#pragma unroll
    for (int g = 0; g < 8; ++g) { ss += red[tid * 8 + g]; s2 += red[2048 + tid * 8 + g]; }
    float mu  = ss * (1.f / 256.f);
    float var = s2 * (1.f / 256.f) - mu * mu;
    mrs[tid]       = mu;
    mrs[256 + tid] = rsqrtf(var + 1e-5f);
  }
  __syncthreads();
  {
    char* dst = (char*)xn_ws + (size_t)((b * NWH + wh) * NWW + wq * 4) * 32768;
#pragma unroll
    for (int it = 0; it < 16; ++it) {
      const int a   = (it * 512 + tid) * 16;
      const int w2  = a >> 15;
      const int ab  = a & 32767;
      const int tok = ab >> 9;
      const int chb = ((ab & 511) ^ ((((tok & 7) ^ ((tok >> 3) & 7))) << 4)) >> 1;
      f16x8 hv = *(const f16x8*)(smem + a);
      const float mu = mrs[w2 * 64 + tok], rs = mrs[256 + w2 * 64 + tok];
      f32x4 g0 = *(const f32x4*)(gamma + chb), g1 = *(const f32x4*)(gamma + chb + 4);
      f32x4 b0 = *(const f32x4*)(beta + chb),  b1 = *(const f32x4*)(beta + chb + 4);
#pragma unroll
      for (int j = 0; j < 4; ++j) {
        hv[j]     = (_Float16)(((float)hv[j] - mu) * rs * g0[j] + b0[j]);
        hv[j + 4] = (_Float16)(((float)hv[j + 4] - mu) * rs * g1[j] + b1[j]);
      }
      *(f16x8*)(dst + a) = hv;
    }
  }
}

// ============================ kernel B: megattn v5 ===========================
// = R14-v3 (proven 238us) + double-buffered weight prefetch (T14 split) and
//   barrier A removed. 512 thr = 8 waves; wave w -> window (w>>1), M-half (w&1).
// LDS 163840 B (exactly 160KB, R3-proven launchable):
//   [0,49152)        weight buf0   [49152,98304) weight buf1
//   [98304,147456)   per-window scratch winl*12288: q 4K | k 4K | vT 4K
//                    (p 8KB overlays q+k after C2)
//   [147456,163840)  per-window o buffer 4KB
// Per head h: issue h+1 weight loads (regs) -> GEMM buf[h&1] -> barrier D ->
//   write regs to buf[(h+1)&1] (vmcnt wait here, latency hidden by GEMM) ->
//   epilogue -> C -> qa/kb -> C2 -> softmax/PV/dump.  3 barriers/head.
// NO launch-bounds min-waves coercion (R9/R15: it forces spills).
__global__ __launch_bounds__(512, 1) void megattn_kernel(
    const float* __restrict__ bqkv, const _Float16* __restrict__ w16,
    const _Float16* __restrict__ xn_ws, _Float16* __restrict__ o_ws) {
  extern __shared__ char smem[];
  const int tid = threadIdx.x;
  const int w = tid >> 6, lane = tid & 63, lr = lane & 15, lg = lane >> 4;
  const int winl = w >> 1;
  const int half = w & 1;
  const int r0   = half * 32;
  const int win  = blockIdx.x * 4 + winl;
  const char* w16b = (const char*)w16;

  // A-fragments for this wave's M-half (32 VGPR), live across all heads
  f16x8 af[2][8];
  {
    const char* xb = (const char*)xn_ws + (size_t)win * 32768;
#pragma unroll
    for (int mi = 0; mi < 2; ++mi)
#pragma unroll
      for (int kk = 0; kk < 8; ++kk)
        af[mi][kk] = *(const f16x8*)(xb + xn_off(r0 + mi * 16 + lr, kk * 32 + lg * 8));
  }

  char* scr   = smem + 98304 + winl * 12288;  // q scratch (p overlays q+k)
  char* kbase = scr + 4096;                   // k scratch
  char* vbase = scr + 8192;                   // vT
  char* obuf  = smem + 147456 + winl * 4096;  // merged o (head-local)
  char* oblob = (char*)o_ws + (size_t)win * 32768;
  const float sc_q = 0.17677669529663687f;    // 1/sqrt(32)

  // ---- prologue: stage head-0 weights into buf0 (reg roundtrip) ----
  {
    f32x4 r[6];
#pragma unroll
    for (int i = 0; i < 6; ++i)
      r[i] = *(const f32x4*)wsrc(w16b, 0, w * 6 + i, lane);
#pragma unroll
    for (int i = 0; i < 6; ++i)
      *(f32x4*)(smem + (w * 6 + i) * 1024 + lane * 16) = r[i];
  }
  __syncthreads();

#pragma unroll 1
  for (int h = 0; h < 8; ++h) {
    // issue next head's weight loads (latency hides under this head's GEMM)
    f32x4 wreg[6];
    if (h < 7) {
#pragma unroll
      for (int i = 0; i < 6; ++i)
        wreg[i] = *(const f32x4*)wsrc(w16b, h + 1, w * 6 + i, lane);
    }

    // ---- GEMM from buf[h&1]: 6 N-tiles x 2 M-tiles = 96 MFMA ----
    char* bufb = smem + (h & 1) * 49152;
    f32x4 acc[6][2];
#pragma unroll
    for (int t = 0; t < 6; ++t)
#pragma unroll
      for (int mi = 0; mi < 2; ++mi) acc[t][mi] = (f32x4){0.f, 0.f, 0.f, 0.f};
#pragma unroll
    for (int kk = 0; kk < 8; ++kk) {
      const int fo = (kk * 64 + lane) * 16;
      f16x8 b0 = *(const f16x8*)(bufb + fo);
      f16x8 b1 = *(const f16x8*)(bufb + 8192 + fo);
      f16x8 b2 = *(const f16x8*)(bufb + 16384 + fo);
      f16x8 b3 = *(const f16x8*)(bufb + 24576 + fo);
      f16x8 b4 = *(const f16x8*)(bufb + 32768 + fo);
      f16x8 b5 = *(const f16x8*)(bufb + 40960 + fo);
#pragma unroll
      for (int mi = 0; mi < 2; ++mi) {
        acc[0][mi] = __builtin_amdgcn_mfma_f32_16x16x32_f16(af[mi][kk], b0, acc[0][mi], 0, 0, 0);
        acc[1][mi] = __builtin_amdgcn_mfma_f32_16x16x32_f16(af[mi][kk], b1, acc[1][mi], 0, 0, 0);
        acc[2][mi] = __builtin_amdgcn_mfma_f32_16x16x32_f16(af[mi][kk], b2, acc[2][mi], 0, 0, 0);
        acc[3][mi] = __builtin_amdgcn_mfma_f32_16x16x32_f16(af[mi][kk], b3, acc[3][mi], 0, 0, 0);
        acc[4][mi] = __builtin_amdgcn_mfma_f32_16x16x32_f16(af[mi][kk], b4, acc[4][mi], 0, 0, 0);
        acc[5][mi] = __builtin_amdgcn_mfma_f32_16x16x32_f16(af[mi][kk], b5, acc[5][mi], 0, 0, 0);
      }
    }
    __syncthreads();   // D: all waves past GEMM h (and prior head's p/vT reads)

    // write prefetched weights for h+1 (buffer last read in GEMM h-1)
    if (h < 7) {
      char* nb = smem + ((h + 1) & 1) * 49152;
#pragma unroll
      for (int i = 0; i < 6; ++i)
        *(f32x4*)(nb + (w * 6 + i) * 1024 + lane * 16) = wreg[i];
    }

    // ---- epilogue: q scaled+bias, k bias, vT (this wave's token half) ----
#pragma unroll
    for (int t2 = 0; t2 < 2; ++t2) {
      const float bq = bqkv[h * 32 + t2 * 16 + lr];
      const float bk = bqkv[256 + h * 32 + t2 * 16 + lr];
      const float bv = bqkv[512 + h * 32 + t2 * 16 + lr];
#pragma unroll
      for (int mi = 0; mi < 2; ++mi)
#pragma unroll
        for (int i = 0; i < 4; ++i) {
          const int trow = r0 + mi * 16 + lg * 4 + i;
          *(_Float16*)(scr + qk_off(trow, t2 * 16 + lr))   = (_Float16)((acc[t2][mi][i] + bq) * sc_q);
          *(_Float16*)(kbase + qk_off(trow, t2 * 16 + lr)) = (_Float16)(acc[2 + t2][mi][i] + bk);
          *(_Float16*)(vbase + vt_off(t2 * 16 + lr, trow)) = (_Float16)(acc[4 + t2][mi][i] + bv);
        }
    }
    __syncthreads();   // C: both halves' q/k/vT visible

    // ---- scores: own q rows x ALL k rows ----
    f16x8 qa[2], kb[4];
#pragma unroll
    for (int mi = 0; mi < 2; ++mi)
      qa[mi] = *(const f16x8*)(scr + qk_off(r0 + mi * 16 + lr, lg * 8));
#pragma unroll
    for (int ni = 0; ni < 4; ++ni)
      kb[ni] = *(const f16x8*)(kbase + qk_off(ni * 16 + lr, lg * 8));
    __syncthreads();   // C2: all waves' qa/kb loaded before p overlays q/k

    float oinv[2][4];
#pragma unroll
    for (int mi = 0; mi < 2; ++mi) {
      f32x4 s4[4];
#pragma unroll
      for (int ni = 0; ni < 4; ++ni) {
        f32x4 z = {0.f, 0.f, 0.f, 0.f};
        s4[ni] = __builtin_amdgcn_mfma_f32_16x16x32_f16(qa[mi], kb[ni], z, 0, 0, 0);
      }
#pragma unroll
      for (int i = 0; i < 4; ++i) {
        float m = fmaxf(fmaxf(s4[0][i], s4[1][i]), fmaxf(s4[2][i], s4[3][i]));
        m = fmaxf(m, __shfl_xor(m, 1));
        m = fmaxf(m, __shfl_xor(m, 2));
        m = fmaxf(m, __shfl_xor(m, 4));
        m = fmaxf(m, __shfl_xor(m, 8));
        float s = 0.f;
#pragma unroll
        for (int ni = 0; ni < 4; ++ni) {
          float e = __expf(s4[ni][i] - m);
          s4[ni][i] = e;
          s += e;
        }
        s += __shfl_xor(s, 1);
        s += __shfl_xor(s, 2);
        s += __shfl_xor(s, 4);
        s += __shfl_xor(s, 8);
        oinv[mi][i] = 1.f / s;
      }
#pragma unroll
      for (int ni = 0; ni < 4; ++ni)
#pragma unroll
        for (int i = 0; i < 4; ++i)
          *(_Float16*)(scr + p_off(r0 + mi * 16 + lg * 4 + i, ni * 16 + lr)) = (_Float16)s4[ni][i];
    }
    // ---- PV: own p rows x all vT ----
    f32x4 oacc[2][2];
#pragma unroll
    for (int mi = 0; mi < 2; ++mi)
#pragma unroll
      for (int nt2 = 0; nt2 < 2; ++nt2) oacc[mi][nt2] = (f32x4){0.f, 0.f, 0.f, 0.f};
#pragma unroll
    for (int ks2 = 0; ks2 < 2; ++ks2) {
      f16x8 pa[2];
#pragma unroll
      for (int mi = 0; mi < 2; ++mi)
        pa[mi] = *(const f16x8*)(scr + p_off(r0 + mi * 16 + lr, ks2 * 32 + lg * 8));
#pragma unroll
      for (int nt2 = 0; nt2 < 2; ++nt2) {
        f16x8 vb = *(const f16x8*)(vbase + vt_off(nt2 * 16 + lr, ks2 * 32 + lg * 8));
#pragma unroll
        for (int mi = 0; mi < 2; ++mi)
          oacc[mi][nt2] = __builtin_amdgcn_mfma_f32_16x16x32_f16(pa[mi], vb, oacc[mi][nt2], 0, 0, 0);
      }
    }
    // ---- o-head: assemble own rows in obuf, dump own 2KB half ----
#pragma unroll
    for (int mi = 0; mi < 2; ++mi)
#pragma unroll
      for (int nt2 = 0; nt2 < 2; ++nt2)
#pragma unroll
        for (int i = 0; i < 4; ++i)
          *(_Float16*)(obuf + qk_off(r0 + mi * 16 + lg * 4 + i, nt2 * 16 + lr)) =
              (_Float16)(oacc[mi][nt2][i] * oinv[mi][i]);
#pragma unroll
    for (int j = 0; j < 2; ++j)
      *(f32x4*)(oblob + h * 4096 + half * 2048 + lane * 32 + j * 16) =
          *(const f32x4*)(obuf + half * 2048 + lane * 32 + j * 16);
  }
}

// ============================ kernel C: out-proj (unchanged) =================
__global__ __launch_bounds__(512, 1) void outproj_kernel(
    const _Float16* __restrict__ o_ws, const _Float16* __restrict__ w16,
    const float* __restrict__ bout, float* __restrict__ out) {
  extern __shared__ char smem[];
  const int n0 = blockIdx.x;
  const int b  = n0 / 196;
  const int rem = n0 % 196;
  const int wh = rem / 7;
  const int wq = rem % 7;
  const int tid = threadIdx.x;
  const int w = tid >> 6, lane = tid & 63, lr = lane & 15, lg = lane >> 4;

  {
    const char* src = (const char*)o_ws + (size_t)((b * NWH + wh) * NWW + wq * 4) * 32768;
#pragma unroll
    for (int it = 0; it < 16; ++it) {
      const int off = (it * 512 + tid) * 16;
      *(f32x4*)(smem + off) = *(const f32x4*)(src + off);
    }
  }
  __syncthreads();

  f32x4 acc[4][2][4];
#pragma unroll
  for (int wi = 0; wi < 4; ++wi)
#pragma unroll
    for (int t = 0; t < 2; ++t)
#pragma unroll
      for (int mi = 0; mi < 4; ++mi) acc[wi][t][mi] = (f32x4){0.f, 0.f, 0.f, 0.f};

#pragma unroll
  for (int kk = 0; kk < 8; ++kk) {   // kk == head of the o blob
    f16x8 bf0 = frag16(w16, 48 + w * 2 + 0, kk, lane);
    f16x8 bf1 = frag16(w16, 48 + w * 2 + 1, kk, lane);
#pragma unroll
    for (int wi = 0; wi < 4; ++wi) {
      f16x8 af[4];
#pragma unroll
      for (int mi = 0; mi < 4; ++mi)
        af[mi] = *(const f16x8*)(smem + wi * 32768 + kk * 4096 + qk_off(mi * 16 + lr, lg * 8));
#pragma unroll
      for (int mi = 0; mi < 4; ++mi) {
        acc[wi][0][mi] = __builtin_amdgcn_mfma_f32_16x16x32_f16(af[mi], bf0, acc[wi][0][mi], 0, 0, 0);
        acc[wi][1][mi] = __builtin_amdgcn_mfma_f32_16x16x32_f16(af[mi], bf1, acc[wi][1][mi], 0, 0, 0);
      }
    }
  }

#pragma unroll
  for (int ntl = 0; ntl < 2; ++ntl) {
    const int och = w * 32 + ntl * 16 + lr;
    const float bias = bout[och];
    float* ob = out + ((size_t)(b * C_ + och) * H_ + wh * 8) * W_ + wq * 32;
#pragma unroll
    for (int mi = 0; mi < 4; ++mi) {
      const int tb = mi * 16 + lg * 4;
      const int ro = (tb >> 3) * W_ + (tb & 7);
#pragma unroll
      for (int wi = 0; wi < 4; ++wi) {
        f32x4 ov;
#pragma unroll
        for (int i = 0; i < 4; ++i) ov[i] = acc[wi][ntl][mi][i] + bias;
        *(f32x4*)&ob[ro + wi * 8] = ov;
      }
    }
  }
}

extern "C" void kernel_launch(void* const* d_in, const int* in_sizes, int n_in,
                              void* d_out, int out_size, void* d_ws, size_t ws_size,
                              hipStream_t stream) {
  (void)in_sizes; (void)n_in; (void)out_size; (void)ws_size;
  const float* x     = (const float*)d_in[0];
  const float* gamma = (const float*)d_in[1];
  const float* beta  = (const float*)d_in[2];
  const float* wqkv  = (const float*)d_in[3];
  const float* bqkv  = (const float*)d_in[4];
  const float* wout  = (const float*)d_in[5];
  const float* bout  = (const float*)d_in[6];
  float* out = (float*)d_out;

  _Float16* w16   = (_Float16*)d_ws;
  _Float16* xn_ws = (_Float16*)((char*)d_ws + XN_OFF);
  _Float16* o_ws  = (_Float16*)((char*)d_ws + O_OFF);

  static int attr_set = 0;
  if (!attr_set) {
    (void)hipFuncSetAttribute((const void*)prep_kernel,
                              hipFuncAttributeMaxDynamicSharedMemorySize, 149504);
    (void)hipFuncSetAttribute((const void*)megattn_kernel,
                              hipFuncAttributeMaxDynamicSharedMemorySize, 163840);
    (void)hipFuncSetAttribute((const void*)outproj_kernel,
                              hipFuncAttributeMaxDynamicSharedMemorySize, 131072);
    attr_set = 1;
  }

  wcvt_kernel<<<NFRAG / 256, 256, 0, stream>>>(wqkv, wout, w16);
  prep_kernel<<<NQUAD, 512, 149504, stream>>>(x, gamma, beta, xn_ws);
  megattn_kernel<<<NQUAD, 512, 163840, stream>>>(bqkv, w16, xn_ws, o_ws);
  outproj_kernel<<<NQUAD, 512, 131072, stream>>>(o_ws, w16, bout, out);
}

// Round 18
// 469.556 us; speedup vs baseline: 1.7392x; 1.1367x over previous
//
#include <hip/hip_runtime.h>
#include <hip/hip_fp16.h>

#define C_   256
#define H_   224
#define W_   224
#define HW_  (224 * 224)
#define NWH  28
#define NWW  28
#define NWIN 3136
#define NQUAD 784
#define NTILE 64
#define NFRAG (NTILE * 8 * 64)

#define XN_OFF (1ULL << 20)
#define O_OFF  (XN_OFF + (unsigned long long)NWIN * 32768ULL)
#define WS_NEED (O_OFF + (unsigned long long)NWIN * 32768ULL)   // 206.6MB, R5-proven fits

typedef _Float16 f16x8 __attribute__((ext_vector_type(8)));
typedef float    f32x4 __attribute__((ext_vector_type(4)));

// ---- byte-offset swizzles (bijective XOR; 16B-aligned) ----------------------
__device__ __forceinline__ int xn_off(int row, int col) {
  return (row * 512 + col * 2) ^ ((((row & 7) ^ ((row >> 3) & 7))) << 4);
}
__device__ __forceinline__ int qk_off(int row, int col) {
  return (row * 64 + col * 2) ^ (((row >> 1) & 3) << 4);
}
__device__ __forceinline__ int vt_off(int d, int k) {
  return (d * 128 + k * 2) ^ ((d & 7) << 4);
}
__device__ __forceinline__ int p_off(int row, int col) {
  return (row * 128 + col * 2) ^ ((row & 7) << 4);
}
__device__ __forceinline__ _Float16* xn_at(char* s, int r, int c) { return (_Float16*)(s + xn_off(r, c)); }

__device__ __forceinline__ f16x8 frag16(const _Float16* __restrict__ w16,
                                        int gt, int kk, int lane) {
  return *(const f16x8*)(w16 + ((size_t)((gt * 8 + kk) * 64 + lane)) * 8);
}

// weight source: head h, 1KB-chunk c (0..47), lane. chunk c -> region c>>4
// (0=q 1=k 2=v, 16KB each = tiles {2h,2h+1}), byte (c&15)*1024 within region.
__device__ __forceinline__ const char* wsrc(const char* w16b, int h, int c, int lane) {
  const int reg = c >> 4;
  const int off = (c & 15) << 10;
  return w16b + (size_t)(reg * 16 + 2 * h) * 8192 + off + lane * 16;
}

// async global->LDS, 16B/lane; dest is the wave-uniform base (HW adds lane*16)
__device__ __forceinline__ void gload_lds16(const char* g, char* l) {
  __builtin_amdgcn_global_load_lds(
      (const __attribute__((address_space(1))) void*)g,
      (__attribute__((address_space(3))) void*)l, 16, 0, 0);
}

// ---- weight fp32 -> fragment-major fp16 ------------------------------------
__global__ void wcvt_kernel(const float* __restrict__ wqkv,
                            const float* __restrict__ wout,
                            _Float16* __restrict__ dst) {
  int f = blockIdx.x * blockDim.x + threadIdx.x;
  if (f >= NFRAG) return;
  int lane = f & 63, kk = (f >> 6) & 7, tile = f >> 9;
  int row = tile * 16 + (lane & 15);
  int col = kk * 32 + (lane >> 4) * 8;
  const float* src = (tile < 48) ? (wqkv + row * 256 + col)
                                 : (wout + (row - 768) * 256 + col);
  f32x4 a = *(const f32x4*)src;
  f32x4 b2 = *(const f32x4*)(src + 4);
  f16x8 r;
#pragma unroll
  for (int q = 0; q < 4; ++q) { r[q] = (_Float16)a[q]; r[q + 4] = (_Float16)b2[q]; }
  *(f16x8*)(dst + (size_t)f * 8) = r;
}

// ============================ kernel A: prep (unchanged) =====================
__global__ __launch_bounds__(512, 1) void prep_kernel(
    const float* __restrict__ x, const float* __restrict__ gamma,
    const float* __restrict__ beta, _Float16* __restrict__ xn_ws) {
  extern __shared__ char smem[];
  float* red = (float*)(smem + 131072);
  float* mrs = (float*)(smem + 147456);
  const int n0 = blockIdx.x;
  const int b  = n0 / 196;
  const int rem = n0 % 196;
  const int wh = rem / 7;
  const int wq = rem % 7;
  const int tid = threadIdx.x;
  const int px4 = (tid & 7) * 4;
  const int row = (tid >> 3) & 7;
  const int chg = tid >> 6;
  const int win = px4 >> 3;
  const int pc  = px4 & 7;
  char* xw = smem + win * 32768;

  {
    const size_t xoff = (size_t)b * C_ * HW_ + (size_t)(wh * 8 + row) * W_ + wq * 32 + px4;
    float s[4] = {0.f, 0.f, 0.f, 0.f}, q[4] = {0.f, 0.f, 0.f, 0.f};
#pragma unroll
    for (int cc = 0; cc < 32; ++cc) {
      const int ch = cc * 8 + chg;
      f32x4 v = *(const f32x4*)(x + xoff + (size_t)ch * HW_);
#pragma unroll
      for (int i = 0; i < 4; ++i) {
        *xn_at(xw, row * 8 + pc + i, ch) = (_Float16)v[i];
        s[i] += v[i]; q[i] += v[i] * v[i];
      }
    }
    const int tq = win * 64 + row * 8 + pc;
#pragma unroll
    for (int i = 0; i < 4; ++i) {
      red[(tq + i) * 8 + chg] = s[i];
      red[2048 + (tq + i) * 8 + chg] = q[i];
    }
  }
  __syncthreads();
  if (tid < 256) {
    float ss = 0.f, s2 = 0.f;
#pragma unroll
    for (int g = 0; g < 8; ++g) { ss += red[tid * 8 + g]; s2 += red[2048 + tid * 8 + g]; }
    float mu  = ss * (1.f / 256.f);
    float var = s2 * (1.f / 256.f) - mu * mu;
    mrs[tid]       = mu;
    mrs[256 + tid] = rsqrtf(var + 1e-5f);
  }
  __syncthreads();
  {
    char* dst = (char*)xn_ws + (size_t)((b * NWH + wh) * NWW + wq * 4) * 32768;
#pragma unroll
    for (int it = 0; it < 16; ++it) {
      const int a   = (it * 512 + tid) * 16;
      const int w2  = a >> 15;
      const int ab  = a & 32767;
      const int tok = ab >> 9;
      const int chb = ((ab & 511) ^ ((((tok & 7) ^ ((tok >> 3) & 7))) << 4)) >> 1;
      f16x8 hv = *(const f16x8*)(smem + a);
      const float mu = mrs[w2 * 64 + tok], rs = mrs[256 + w2 * 64 + tok];
      f32x4 g0 = *(const f32x4*)(gamma + chb), g1 = *(const f32x4*)(gamma + chb + 4);
      f32x4 b0 = *(const f32x4*)(beta + chb),  b1 = *(const f32x4*)(beta + chb + 4);
#pragma unroll
      for (int j = 0; j < 4; ++j) {
        hv[j]     = (_Float16)(((float)hv[j] - mu) * rs * g0[j] + b0[j]);
        hv[j + 4] = (_Float16)(((float)hv[j + 4] - mu) * rs * g1[j] + b1[j]);
      }
      *(f16x8*)(dst + a) = hv;
    }
  }
}

// ============================ kernel B: megattn v6 ===========================
// = R14-v3 structure + double-buffered weight staging via ASYNC global_load_lds
//   (zero VGPR cost -- R17 proved a register-based prefetch clamps at 128 VGPR
//   and spills, WRITE 100->359MB). 512 thr = 8 waves; wave w -> window (w>>1),
//   M-half (w&1). NO launch-bounds min-waves coercion (R9/R15 lessons).
// LDS 163840 B:
//   [0,49152) weight buf0 | [49152,98304) weight buf1
//   [98304,147456)  per-window scratch winl*12288: q 4K | k 4K | vT 4K
//                   (p 8KB overlays q+k after C2)
//   [147456,163840) per-window o buffer 4KB
// Per head h: issue 6 async DMAs for head h+1 into buf[(h+1)&1] (last read in
//   GEMM h-1; all waves past it) -> GEMM buf[h&1] -> D (vmcnt drained here;
//   also orders prior-head p/vT reads vs epilogue) -> epilogue -> C -> qa/kb
//   -> C2 -> softmax -> PV -> dump. 3 barriers/head.
__global__ __launch_bounds__(512, 1) void megattn_kernel(
    const float* __restrict__ bqkv, const _Float16* __restrict__ w16,
    const _Float16* __restrict__ xn_ws, _Float16* __restrict__ o_ws) {
  extern __shared__ char smem[];
  const int tid = threadIdx.x;
  const int w = tid >> 6, lane = tid & 63, lr = lane & 15, lg = lane >> 4;
  const int winl = w >> 1;
  const int half = w & 1;
  const int r0   = half * 32;
  const int win  = blockIdx.x * 4 + winl;
  const char* w16b = (const char*)w16;

  // A-fragments for this wave's M-half (32 VGPR), live across all heads
  f16x8 af[2][8];
  {
    const char* xb = (const char*)xn_ws + (size_t)win * 32768;
#pragma unroll
    for (int mi = 0; mi < 2; ++mi)
#pragma unroll
      for (int kk = 0; kk < 8; ++kk)
        af[mi][kk] = *(const f16x8*)(xb + xn_off(r0 + mi * 16 + lr, kk * 32 + lg * 8));
  }

  char* scr   = smem + 98304 + winl * 12288;  // q scratch (p overlays q+k)
  char* kbase = scr + 4096;                   // k scratch
  char* vbase = scr + 8192;                   // vT
  char* obuf  = smem + 147456 + winl * 4096;  // merged o (head-local)
  char* oblob = (char*)o_ws + (size_t)win * 32768;
  const float sc_q = 0.17677669529663687f;    // 1/sqrt(32)

  // ---- prologue: async-stage head-0 weights into buf0 ----
#pragma unroll
  for (int i = 0; i < 6; ++i)
    gload_lds16(wsrc(w16b, 0, w * 6 + i, lane), smem + (w * 6 + i) * 1024);
  __syncthreads();   // drains vmcnt -> buf0 ready

#pragma unroll 1
  for (int h = 0; h < 8; ++h) {
    // issue next head's async staging (buffer last read in GEMM h-1)
    if (h < 7) {
      char* nb = smem + ((h + 1) & 1) * 49152;
#pragma unroll
      for (int i = 0; i < 6; ++i)
        gload_lds16(wsrc(w16b, h + 1, w * 6 + i, lane), nb + (w * 6 + i) * 1024);
    }

    // ---- GEMM from buf[h&1]: 6 N-tiles x 2 M-tiles = 96 MFMA ----
    char* bufb = smem + (h & 1) * 49152;
    f32x4 acc[6][2];
#pragma unroll
    for (int t = 0; t < 6; ++t)
#pragma unroll
      for (int mi = 0; mi < 2; ++mi) acc[t][mi] = (f32x4){0.f, 0.f, 0.f, 0.f};
#pragma unroll
    for (int kk = 0; kk < 8; ++kk) {
      const int fo = (kk * 64 + lane) * 16;
      f16x8 b0 = *(const f16x8*)(bufb + fo);
      f16x8 b1 = *(const f16x8*)(bufb + 8192 + fo);
      f16x8 b2 = *(const f16x8*)(bufb + 16384 + fo);
      f16x8 b3 = *(const f16x8*)(bufb + 24576 + fo);
      f16x8 b4 = *(const f16x8*)(bufb + 32768 + fo);
      f16x8 b5 = *(const f16x8*)(bufb + 40960 + fo);
#pragma unroll
      for (int mi = 0; mi < 2; ++mi) {
        acc[0][mi] = __builtin_amdgcn_mfma_f32_16x16x32_f16(af[mi][kk], b0, acc[0][mi], 0, 0, 0);
        acc[1][mi] = __builtin_amdgcn_mfma_f32_16x16x32_f16(af[mi][kk], b1, acc[1][mi], 0, 0, 0);
        acc[2][mi] = __builtin_amdgcn_mfma_f32_16x16x32_f16(af[mi][kk], b2, acc[2][mi], 0, 0, 0);
        acc[3][mi] = __builtin_amdgcn_mfma_f32_16x16x32_f16(af[mi][kk], b3, acc[3][mi], 0, 0, 0);
        acc[4][mi] = __builtin_amdgcn_mfma_f32_16x16x32_f16(af[mi][kk], b4, acc[4][mi], 0, 0, 0);
        acc[5][mi] = __builtin_amdgcn_mfma_f32_16x16x32_f16(af[mi][kk], b5, acc[5][mi], 0, 0, 0);
      }
    }
    __syncthreads();   // D: DMA drained; all waves past GEMM h and h-1 tails

    // ---- epilogue: q scaled+bias, k bias, vT (this wave's token half) ----
#pragma unroll
    for (int t2 = 0; t2 < 2; ++t2) {
      const float bq = bqkv[h * 32 + t2 * 16 + lr];
      const float bk = bqkv[256 + h * 32 + t2 * 16 + lr];
      const float bv = bqkv[512 + h * 32 + t2 * 16 + lr];
#pragma unroll
      for (int mi = 0; mi < 2; ++mi)
#pragma unroll
        for (int i = 0; i < 4; ++i) {
          const int trow = r0 + mi * 16 + lg * 4 + i;
          *(_Float16*)(scr + qk_off(trow, t2 * 16 + lr))   = (_Float16)((acc[t2][mi][i] + bq) * sc_q);
          *(_Float16*)(kbase + qk_off(trow, t2 * 16 + lr)) = (_Float16)(acc[2 + t2][mi][i] + bk);
          *(_Float16*)(vbase + vt_off(t2 * 16 + lr, trow)) = (_Float16)(acc[4 + t2][mi][i] + bv);
        }
    }
    __syncthreads();   // C: both halves' q/k/vT visible

    // ---- scores: own q rows x ALL k rows ----
    f16x8 qa[2], kb[4];
#pragma unroll
    for (int mi = 0; mi < 2; ++mi)
      qa[mi] = *(const f16x8*)(scr + qk_off(r0 + mi * 16 + lr, lg * 8));
#pragma unroll
    for (int ni = 0; ni < 4; ++ni)
      kb[ni] = *(const f16x8*)(kbase + qk_off(ni * 16 + lr, lg * 8));
    __syncthreads();   // C2: all waves' qa/kb loaded before p overlays q/k

    float oinv[2][4];
#pragma unroll
    for (int mi = 0; mi < 2; ++mi) {
      f32x4 s4[4];
#pragma unroll
      for (int ni = 0; ni < 4; ++ni) {
        f32x4 z = {0.f, 0.f, 0.f, 0.f};
        s4[ni] = __builtin_amdgcn_mfma_f32_16x16x32_f16(qa[mi], kb[ni], z, 0, 0, 0);
      }
#pragma unroll
      for (int i = 0; i < 4; ++i) {
        float m = fmaxf(fmaxf(s4[0][i], s4[1][i]), fmaxf(s4[2][i], s4[3][i]));
        m = fmaxf(m, __shfl_xor(m, 1));
        m = fmaxf(m, __shfl_xor(m, 2));
        m = fmaxf(m, __shfl_xor(m, 4));
        m = fmaxf(m, __shfl_xor(m, 8));
        float s = 0.f;
#pragma unroll
        for (int ni = 0; ni < 4; ++ni) {
          float e = __expf(s4[ni][i] - m);
          s4[ni][i] = e;
          s += e;
        }
        s += __shfl_xor(s, 1);
        s += __shfl_xor(s, 2);
        s += __shfl_xor(s, 4);
        s += __shfl_xor(s, 8);
        oinv[mi][i] = 1.f / s;
      }
#pragma unroll
      for (int ni = 0; ni < 4; ++ni)
#pragma unroll
        for (int i = 0; i < 4; ++i)
          *(_Float16*)(scr + p_off(r0 + mi * 16 + lg * 4 + i, ni * 16 + lr)) = (_Float16)s4[ni][i];
    }
    // ---- PV: own p rows x all vT ----
    f32x4 oacc[2][2];
#pragma unroll
    for (int mi = 0; mi < 2; ++mi)
#pragma unroll
      for (int nt2 = 0; nt2 < 2; ++nt2) oacc[mi][nt2] = (f32x4){0.f, 0.f, 0.f, 0.f};
#pragma unroll
    for (int ks2 = 0; ks2 < 2; ++ks2) {
      f16x8 pa[2];
#pragma unroll
      for (int mi = 0; mi < 2; ++mi)
        pa[mi] = *(const f16x8*)(scr + p_off(r0 + mi * 16 + lr, ks2 * 32 + lg * 8));
#pragma unroll
      for (int nt2 = 0; nt2 < 2; ++nt2) {
        f16x8 vb = *(const f16x8*)(vbase + vt_off(nt2 * 16 + lr, ks2 * 32 + lg * 8));
#pragma unroll
        for (int mi = 0; mi < 2; ++mi)
          oacc[mi][nt2] = __builtin_amdgcn_mfma_f32_16x16x32_f16(pa[mi], vb, oacc[mi][nt2], 0, 0, 0);
      }
    }
    // ---- o-head: assemble own rows in obuf, dump own 2KB half ----
#pragma unroll
    for (int mi = 0; mi < 2; ++mi)
#pragma unroll
      for (int nt2 = 0; nt2 < 2; ++nt2)
#pragma unroll
        for (int i = 0; i < 4; ++i)
          *(_Float16*)(obuf + qk_off(r0 + mi * 16 + lg * 4 + i, nt2 * 16 + lr)) =
              (_Float16)(oacc[mi][nt2][i] * oinv[mi][i]);
#pragma unroll
    for (int j = 0; j < 2; ++j)
      *(f32x4*)(oblob + h * 4096 + half * 2048 + lane * 32 + j * 16) =
          *(const f32x4*)(obuf + half * 2048 + lane * 32 + j * 16);
  }
}

// ============================ kernel C: out-proj (unchanged) =================
__global__ __launch_bounds__(512, 1) void outproj_kernel(
    const _Float16* __restrict__ o_ws, const _Float16* __restrict__ w16,
    const float* __restrict__ bout, float* __restrict__ out) {
  extern __shared__ char smem[];
  const int n0 = blockIdx.x;
  const int b  = n0 / 196;
  const int rem = n0 % 196;
  const int wh = rem / 7;
  const int wq = rem % 7;
  const int tid = threadIdx.x;
  const int w = tid >> 6, lane = tid & 63, lr = lane & 15, lg = lane >> 4;

  {
    const char* src = (const char*)o_ws + (size_t)((b * NWH + wh) * NWW + wq * 4) * 32768;
#pragma unroll
    for (int it = 0; it < 16; ++it) {
      const int off = (it * 512 + tid) * 16;
      *(f32x4*)(smem + off) = *(const f32x4*)(src + off);
    }
  }
  __syncthreads();

  f32x4 acc[4][2][4];
#pragma unroll
  for (int wi = 0; wi < 4; ++wi)
#pragma unroll
    for (int t = 0; t < 2; ++t)
#pragma unroll
      for (int mi = 0; mi < 4; ++mi) acc[wi][t][mi] = (f32x4){0.f, 0.f, 0.f, 0.f};

#pragma unroll
  for (int kk = 0; kk < 8; ++kk) {   // kk == head of the o blob
    f16x8 bf0 = frag16(w16, 48 + w * 2 + 0, kk, lane);
    f16x8 bf1 = frag16(w16, 48 + w * 2 + 1, kk, lane);
#pragma unroll
    for (int wi = 0; wi < 4; ++wi) {
      f16x8 af[4];
#pragma unroll
      for (int mi = 0; mi < 4; ++mi)
        af[mi] = *(const f16x8*)(smem + wi * 32768 + kk * 4096 + qk_off(mi * 16 + lr, lg * 8));
#pragma unroll
      for (int mi = 0; mi < 4; ++mi) {
        acc[wi][0][mi] = __builtin_amdgcn_mfma_f32_16x16x32_f16(af[mi], bf0, acc[wi][0][mi], 0, 0, 0);
        acc[wi][1][mi] = __builtin_amdgcn_mfma_f32_16x16x32_f16(af[mi], bf1, acc[wi][1][mi], 0, 0, 0);
      }
    }
  }

#pragma unroll
  for (int ntl = 0; ntl < 2; ++ntl) {
    const int och = w * 32 + ntl * 16 + lr;
    const float bias = bout[och];
    float* ob = out + ((size_t)(b * C_ + och) * H_ + wh * 8) * W_ + wq * 32;
#pragma unroll
    for (int mi = 0; mi < 4; ++mi) {
      const int tb = mi * 16 + lg * 4;
      const int ro = (tb >> 3) * W_ + (tb & 7);
#pragma unroll
      for (int wi = 0; wi < 4; ++wi) {
        f32x4 ov;
#pragma unroll
        for (int i = 0; i < 4; ++i) ov[i] = acc[wi][ntl][mi][i] + bias;
        *(f32x4*)&ob[ro + wi * 8] = ov;
      }
    }
  }
}

extern "C" void kernel_launch(void* const* d_in, const int* in_sizes, int n_in,
                              void* d_out, int out_size, void* d_ws, size_t ws_size,
                              hipStream_t stream) {
  (void)in_sizes; (void)n_in; (void)out_size; (void)ws_size;
  const float* x     = (const float*)d_in[0];
  const float* gamma = (const float*)d_in[1];
  const float* beta  = (const float*)d_in[2];
  const float* wqkv  = (const float*)d_in[3];
  const float* bqkv  = (const float*)d_in[4];
  const float* wout  = (const float*)d_in[5];
  const float* bout  = (const float*)d_in[6];
  float* out = (float*)d_out;

  _Float16* w16   = (_Float16*)d_ws;
  _Float16* xn_ws = (_Float16*)((char*)d_ws + XN_OFF);
  _Float16* o_ws  = (_Float16*)((char*)d_ws + O_OFF);

  static int attr_set = 0;
  if (!attr_set) {
    (void)hipFuncSetAttribute((const void*)prep_kernel,
                              hipFuncAttributeMaxDynamicSharedMemorySize, 149504);
    (void)hipFuncSetAttribute((const void*)megattn_kernel,
                              hipFuncAttributeMaxDynamicSharedMemorySize, 163840);
    (void)hipFuncSetAttribute((const void*)outproj_kernel,
                              hipFuncAttributeMaxDynamicSharedMemorySize, 131072);
    attr_set = 1;
  }

  wcvt_kernel<<<NFRAG / 256, 256, 0, stream>>>(wqkv, wout, w16);
  prep_kernel<<<NQUAD, 512, 149504, stream>>>(x, gamma, beta, xn_ws);
  megattn_kernel<<<NQUAD, 512, 163840, stream>>>(bqkv, w16, xn_ws, o_ws);
  outproj_kernel<<<NQUAD, 512, 131072, stream>>>(o_ws, w16, bout, out);
}

// Round 19
// 411.652 us; speedup vs baseline: 1.9838x; 1.1407x over previous
//
#include <hip/hip_runtime.h>
#include <hip/hip_fp16.h>

#define C_   256
#define H_   224
#define W_   224
#define HW_  (224 * 224)
#define NWH  28
#define NWW  28
#define NWIN 3136
#define NQUAD 784
#define NTILE 64
#define NFRAG (NTILE * 8 * 64)

#define XN_OFF (1ULL << 20)
#define O_OFF  (XN_OFF + (unsigned long long)NWIN * 32768ULL)
#define WS_NEED (O_OFF + (unsigned long long)NWIN * 32768ULL)   // 206.6MB, R5-proven fits

typedef _Float16 f16x8 __attribute__((ext_vector_type(8)));
typedef float    f32x4 __attribute__((ext_vector_type(4)));

// ---- byte-offset swizzles (bijective XOR; 16B-aligned) ----------------------
__device__ __forceinline__ int xn_off(int row, int col) {
  return (row * 512 + col * 2) ^ ((((row & 7) ^ ((row >> 3) & 7))) << 4);
}
__device__ __forceinline__ int qk_off(int row, int col) {
  return (row * 64 + col * 2) ^ (((row >> 1) & 3) << 4);
}
__device__ __forceinline__ int vt_off(int d, int k) {
  return (d * 128 + k * 2) ^ ((d & 7) << 4);
}
__device__ __forceinline__ int p_off(int row, int col) {
  return (row * 128 + col * 2) ^ ((row & 7) << 4);
}
__device__ __forceinline__ _Float16* xn_at(char* s, int r, int c) { return (_Float16*)(s + xn_off(r, c)); }

// ---- weight fp32 -> fragment-major fp16 ------------------------------------
__global__ void wcvt_kernel(const float* __restrict__ wqkv,
                            const float* __restrict__ wout,
                            _Float16* __restrict__ dst) {
  int f = blockIdx.x * blockDim.x + threadIdx.x;
  if (f >= NFRAG) return;
  int lane = f & 63, kk = (f >> 6) & 7, tile = f >> 9;
  int row = tile * 16 + (lane & 15);
  int col = kk * 32 + (lane >> 4) * 8;
  const float* src = (tile < 48) ? (wqkv + row * 256 + col)
                                 : (wout + (row - 768) * 256 + col);
  f32x4 a = *(const f32x4*)src;
  f32x4 b2 = *(const f32x4*)(src + 4);
  f16x8 r;
#pragma unroll
  for (int q = 0; q < 4; ++q) { r[q] = (_Float16)a[q]; r[q + 4] = (_Float16)b2[q]; }
  *(f16x8*)(dst + (size_t)f * 8) = r;
}

// ============================ kernel A: prep (unchanged) =====================
__global__ __launch_bounds__(512, 1) void prep_kernel(
    const float* __restrict__ x, const float* __restrict__ gamma,
    const float* __restrict__ beta, _Float16* __restrict__ xn_ws) {
  extern __shared__ char smem[];
  float* red = (float*)(smem + 131072);
  float* mrs = (float*)(smem + 147456);
  const int n0 = blockIdx.x;
  const int b  = n0 / 196;
  const int rem = n0 % 196;
  const int wh = rem / 7;
  const int wq = rem % 7;
  const int tid = threadIdx.x;
  const int px4 = (tid & 7) * 4;
  const int row = (tid >> 3) & 7;
  const int chg = tid >> 6;
  const int win = px4 >> 3;
  const int pc  = px4 & 7;
  char* xw = smem + win * 32768;

  {
    const size_t xoff = (size_t)b * C_ * HW_ + (size_t)(wh * 8 + row) * W_ + wq * 32 + px4;
    float s[4] = {0.f, 0.f, 0.f, 0.f}, q[4] = {0.f, 0.f, 0.f, 0.f};
#pragma unroll
    for (int cc = 0; cc < 32; ++cc) {
      const int ch = cc * 8 + chg;
      f32x4 v = *(const f32x4*)(x + xoff + (size_t)ch * HW_);
#pragma unroll
      for (int i = 0; i < 4; ++i) {
        *xn_at(xw, row * 8 + pc + i, ch) = (_Float16)v[i];
        s[i] += v[i]; q[i] += v[i] * v[i];
      }
    }
    const int tq = win * 64 + row * 8 + pc;
#pragma unroll
    for (int i = 0; i < 4; ++i) {
      red[(tq + i) * 8 + chg] = s[i];
      red[2048 + (tq + i) * 8 + chg] = q[i];
    }
  }
  __syncthreads();
  if (tid < 256) {
    float ss = 0.f, s2 = 0.f;
#pragma unroll
    for (int g = 0; g < 8; ++g) { ss += red[tid * 8 + g]; s2 += red[2048 + tid * 8 + g]; }
    float mu  = ss * (1.f / 256.f);
    float var = s2 * (1.f / 256.f) - mu * mu;
    mrs[tid]       = mu;
    mrs[256 + tid] = rsqrtf(var + 1e-5f);
  }
  __syncthreads();
  {
    char* dst = (char*)xn_ws + (size_t)((b * NWH + wh) * NWW + wq * 4) * 32768;
#pragma unroll
    for (int it = 0; it < 16; ++it) {
      const int a   = (it * 512 + tid) * 16;
      const int w2  = a >> 15;
      const int ab  = a & 32767;
      const int tok = ab >> 9;
      const int chb = ((ab & 511) ^ ((((tok & 7) ^ ((tok >> 3) & 7))) << 4)) >> 1;
      f16x8 hv = *(const f16x8*)(smem + a);
      const float mu = mrs[w2 * 64 + tok], rs = mrs[256 + w2 * 64 + tok];
      f32x4 g0 = *(const f32x4*)(gamma + chb), g1 = *(const f32x4*)(gamma + chb + 4);
      f32x4 b0 = *(const f32x4*)(beta + chb),  b1 = *(const f32x4*)(beta + chb + 4);
#pragma unroll
      for (int j = 0; j < 4; ++j) {
        hv[j]     = (_Float16)(((float)hv[j] - mu) * rs * g0[j] + b0[j]);
        hv[j + 4] = (_Float16)(((float)hv[j + 4] - mu) * rs * g1[j] + b1[j]);
      }
      *(f16x8*)(dst + a) = hv;
    }
  }
}

// ============================ kernel B: megattn v3 (R14 EXACT, 238us) ========
// 512 thr = 8 waves; wave w -> window (w>>1), M-half (w&1) rows [32h,32h+32).
// 2 waves/SIMD guaranteed within the single block. LDS 114688 B:
//   [0,49152)       head weights q|k|v (16KB each)
//   [49152,98304)   per-window scratch winl*12288: q 4K | k 4K | vT 4K
//                   (p 8KB overlays q+k after C2)
//   [98304,114688)  per-window o buffer 4KB
// Proven best (R14: 238us, VGPR 124). R15/R17/R18 staging variants all lost
// (462/361/297) — the 128-VGPR band clamps & spills any prefetch state, and
// launch-bounds min-waves>1 always forces spills (R9/R15). Do not touch.
__global__ __launch_bounds__(512, 1) void megattn_kernel(
    const float* __restrict__ bqkv, const _Float16* __restrict__ w16,
    const _Float16* __restrict__ xn_ws, _Float16* __restrict__ o_ws) {
  extern __shared__ char smem[];
  const int tid = threadIdx.x;
  const int w = tid >> 6, lane = tid & 63, lr = lane & 15, lg = lane >> 4;
  const int winl = w >> 1;
  const int half = w & 1;
  const int r0   = half * 32;
  const int win  = blockIdx.x * 4 + winl;

  // A-fragments for this wave's M-half (64 VGPR)
  f16x8 af[2][8];
  {
    const char* xb = (const char*)xn_ws + (size_t)win * 32768;
#pragma unroll
    for (int mi = 0; mi < 2; ++mi)
#pragma unroll
      for (int kk = 0; kk < 8; ++kk)
        af[mi][kk] = *(const f16x8*)(xb + xn_off(r0 + mi * 16 + lr, kk * 32 + lg * 8));
  }

  char* scr   = smem + 49152 + winl * 12288;  // q scratch (p overlays q+k)
  char* kbase = scr + 4096;                   // k scratch
  char* vbase = scr + 8192;                   // vT
  char* obuf  = smem + 98304 + winl * 4096;   // merged o (head-local)
  char* oblob = (char*)o_ws + (size_t)win * 32768;
  const float sc_q = 0.17677669529663687f;    // 1/sqrt(32)

#pragma unroll 1
  for (int h = 0; h < 8; ++h) {
    __syncthreads();   // A: prior head done with weights + scratch
    {
      const char* s0 = (const char*)w16 + (size_t)(2 * h) * 8192;
      const char* s1 = (const char*)w16 + (size_t)(16 + 2 * h) * 8192;
      const char* s2 = (const char*)w16 + (size_t)(32 + 2 * h) * 8192;
#pragma unroll
      for (int it = 0; it < 2; ++it) {
        const int o = (it * 512 + tid) * 16;
        *(f32x4*)(smem + o)         = *(const f32x4*)(s0 + o);
        *(f32x4*)(smem + 16384 + o) = *(const f32x4*)(s1 + o);
        *(f32x4*)(smem + 32768 + o) = *(const f32x4*)(s2 + o);
      }
    }
    __syncthreads();   // B: weights staged

    // ---- GEMM: 6 N-tiles x 2 M-tiles (this wave's half) = 96 MFMA ----
    f32x4 acc[6][2];
#pragma unroll
    for (int t = 0; t < 6; ++t)
#pragma unroll
      for (int mi = 0; mi < 2; ++mi) acc[t][mi] = (f32x4){0.f, 0.f, 0.f, 0.f};
#pragma unroll
    for (int kk = 0; kk < 8; ++kk) {
      const int fo = (kk * 64 + lane) * 16;
      f16x8 b0 = *(const f16x8*)(smem + fo);
      f16x8 b1 = *(const f16x8*)(smem + 8192 + fo);
      f16x8 b2 = *(const f16x8*)(smem + 16384 + fo);
      f16x8 b3 = *(const f16x8*)(smem + 24576 + fo);
      f16x8 b4 = *(const f16x8*)(smem + 32768 + fo);
      f16x8 b5 = *(const f16x8*)(smem + 40960 + fo);
#pragma unroll
      for (int mi = 0; mi < 2; ++mi) {
        acc[0][mi] = __builtin_amdgcn_mfma_f32_16x16x32_f16(af[mi][kk], b0, acc[0][mi], 0, 0, 0);
        acc[1][mi] = __builtin_amdgcn_mfma_f32_16x16x32_f16(af[mi][kk], b1, acc[1][mi], 0, 0, 0);
        acc[2][mi] = __builtin_amdgcn_mfma_f32_16x16x32_f16(af[mi][kk], b2, acc[2][mi], 0, 0, 0);
        acc[3][mi] = __builtin_amdgcn_mfma_f32_16x16x32_f16(af[mi][kk], b3, acc[3][mi], 0, 0, 0);
        acc[4][mi] = __builtin_amdgcn_mfma_f32_16x16x32_f16(af[mi][kk], b4, acc[4][mi], 0, 0, 0);
        acc[5][mi] = __builtin_amdgcn_mfma_f32_16x16x32_f16(af[mi][kk], b5, acc[5][mi], 0, 0, 0);
      }
    }
    // ---- epilogue: q scaled+bias, k bias, vT (this wave's token half) ----
#pragma unroll
    for (int t2 = 0; t2 < 2; ++t2) {
      const float bq = bqkv[h * 32 + t2 * 16 + lr];
      const float bk = bqkv[256 + h * 32 + t2 * 16 + lr];
      const float bv = bqkv[512 + h * 32 + t2 * 16 + lr];
#pragma unroll
      for (int mi = 0; mi < 2; ++mi)
#pragma unroll
        for (int i = 0; i < 4; ++i) {
          const int trow = r0 + mi * 16 + lg * 4 + i;
          *(_Float16*)(scr + qk_off(trow, t2 * 16 + lr))   = (_Float16)((acc[t2][mi][i] + bq) * sc_q);
          *(_Float16*)(kbase + qk_off(trow, t2 * 16 + lr)) = (_Float16)(acc[2 + t2][mi][i] + bk);
          *(_Float16*)(vbase + vt_off(t2 * 16 + lr, trow)) = (_Float16)(acc[4 + t2][mi][i] + bv);
        }
    }
    __syncthreads();   // C: both halves' q/k/vT visible

    // ---- scores: own q rows x ALL k rows ----
    f16x8 qa[2], kb[4];
#pragma unroll
    for (int mi = 0; mi < 2; ++mi)
      qa[mi] = *(const f16x8*)(scr + qk_off(r0 + mi * 16 + lr, lg * 8));
#pragma unroll
    for (int ni = 0; ni < 4; ++ni)
      kb[ni] = *(const f16x8*)(kbase + qk_off(ni * 16 + lr, lg * 8));
    __syncthreads();   // C2: all waves' qa/kb loaded before p overlays q/k

    float oinv[2][4];
#pragma unroll
    for (int mi = 0; mi < 2; ++mi) {
      f32x4 s4[4];
#pragma unroll
      for (int ni = 0; ni < 4; ++ni) {
        f32x4 z = {0.f, 0.f, 0.f, 0.f};
        s4[ni] = __builtin_amdgcn_mfma_f32_16x16x32_f16(qa[mi], kb[ni], z, 0, 0, 0);
      }
#pragma unroll
      for (int i = 0; i < 4; ++i) {
        float m = fmaxf(fmaxf(s4[0][i], s4[1][i]), fmaxf(s4[2][i], s4[3][i]));
        m = fmaxf(m, __shfl_xor(m, 1));
        m = fmaxf(m, __shfl_xor(m, 2));
        m = fmaxf(m, __shfl_xor(m, 4));
        m = fmaxf(m, __shfl_xor(m, 8));
        float s = 0.f;
#pragma unroll
        for (int ni = 0; ni < 4; ++ni) {
          float e = __expf(s4[ni][i] - m);
          s4[ni][i] = e;
          s += e;
        }
        s += __shfl_xor(s, 1);
        s += __shfl_xor(s, 2);
        s += __shfl_xor(s, 4);
        s += __shfl_xor(s, 8);
        oinv[mi][i] = 1.f / s;
      }
#pragma unroll
      for (int ni = 0; ni < 4; ++ni)
#pragma unroll
        for (int i = 0; i < 4; ++i)
          *(_Float16*)(scr + p_off(r0 + mi * 16 + lg * 4 + i, ni * 16 + lr)) = (_Float16)s4[ni][i];
    }
    // ---- PV: own p rows x all vT ----
    f32x4 oacc[2][2];
#pragma unroll
    for (int mi = 0; mi < 2; ++mi)
#pragma unroll
      for (int nt2 = 0; nt2 < 2; ++nt2) oacc[mi][nt2] = (f32x4){0.f, 0.f, 0.f, 0.f};
#pragma unroll
    for (int ks2 = 0; ks2 < 2; ++ks2) {
      f16x8 pa[2];
#pragma unroll
      for (int mi = 0; mi < 2; ++mi)
        pa[mi] = *(const f16x8*)(scr + p_off(r0 + mi * 16 + lr, ks2 * 32 + lg * 8));
#pragma unroll
      for (int nt2 = 0; nt2 < 2; ++nt2) {
        f16x8 vb = *(const f16x8*)(vbase + vt_off(nt2 * 16 + lr, ks2 * 32 + lg * 8));
#pragma unroll
        for (int mi = 0; mi < 2; ++mi)
          oacc[mi][nt2] = __builtin_amdgcn_mfma_f32_16x16x32_f16(pa[mi], vb, oacc[mi][nt2], 0, 0, 0);
      }
    }
    // ---- o-head: assemble own rows in obuf, dump own 2KB half ----
#pragma unroll
    for (int mi = 0; mi < 2; ++mi)
#pragma unroll
      for (int nt2 = 0; nt2 < 2; ++nt2)
#pragma unroll
        for (int i = 0; i < 4; ++i)
          *(_Float16*)(obuf + qk_off(r0 + mi * 16 + lg * 4 + i, nt2 * 16 + lr)) =
              (_Float16)(oacc[mi][nt2][i] * oinv[mi][i]);
#pragma unroll
    for (int j = 0; j < 2; ++j)
      *(f32x4*)(oblob + h * 4096 + half * 2048 + lane * 32 + j * 16) =
          *(const f32x4*)(obuf + half * 2048 + lane * 32 + j * 16);
  }
}

// ============================ kernel C: out-proj (unchanged) =================
__device__ __forceinline__ f16x8 frag16(const _Float16* __restrict__ w16,
                                        int gt, int kk, int lane) {
  return *(const f16x8*)(w16 + ((size_t)((gt * 8 + kk) * 64 + lane)) * 8);
}
__global__ __launch_bounds__(512, 1) void outproj_kernel(
    const _Float16* __restrict__ o_ws, const _Float16* __restrict__ w16,
    const float* __restrict__ bout, float* __restrict__ out) {
  extern __shared__ char smem[];
  const int n0 = blockIdx.x;
  const int b  = n0 / 196;
  const int rem = n0 % 196;
  const int wh = rem / 7;
  const int wq = rem % 7;
  const int tid = threadIdx.x;
  const int w = tid >> 6, lane = tid & 63, lr = lane & 15, lg = lane >> 4;

  {
    const char* src = (const char*)o_ws + (size_t)((b * NWH + wh) * NWW + wq * 4) * 32768;
#pragma unroll
    for (int it = 0; it < 16; ++it) {
      const int off = (it * 512 + tid) * 16;
      *(f32x4*)(smem + off) = *(const f32x4*)(src + off);
    }
  }
  __syncthreads();

  f32x4 acc[4][2][4];
#pragma unroll
  for (int wi = 0; wi < 4; ++wi)
#pragma unroll
    for (int t = 0; t < 2; ++t)
#pragma unroll
      for (int mi = 0; mi < 4; ++mi) acc[wi][t][mi] = (f32x4){0.f, 0.f, 0.f, 0.f};

#pragma unroll
  for (int kk = 0; kk < 8; ++kk) {   // kk == head of the o blob
    f16x8 bf0 = frag16(w16, 48 + w * 2 + 0, kk, lane);
    f16x8 bf1 = frag16(w16, 48 + w * 2 + 1, kk, lane);
#pragma unroll
    for (int wi = 0; wi < 4; ++wi) {
      f16x8 af[4];
#pragma unroll
      for (int mi = 0; mi < 4; ++mi)
        af[mi] = *(const f16x8*)(smem + wi * 32768 + kk * 4096 + qk_off(mi * 16 + lr, lg * 8));
#pragma unroll
      for (int mi = 0; mi < 4; ++mi) {
        acc[wi][0][mi] = __builtin_amdgcn_mfma_f32_16x16x32_f16(af[mi], bf0, acc[wi][0][mi], 0, 0, 0);
        acc[wi][1][mi] = __builtin_amdgcn_mfma_f32_16x16x32_f16(af[mi], bf1, acc[wi][1][mi], 0, 0, 0);
      }
    }
  }

#pragma unroll
  for (int ntl = 0; ntl < 2; ++ntl) {
    const int och = w * 32 + ntl * 16 + lr;
    const float bias = bout[och];
    float* ob = out + ((size_t)(b * C_ + och) * H_ + wh * 8) * W_ + wq * 32;
#pragma unroll
    for (int mi = 0; mi < 4; ++mi) {
      const int tb = mi * 16 + lg * 4;
      const int ro = (tb >> 3) * W_ + (tb & 7);
#pragma unroll
      for (int wi = 0; wi < 4; ++wi) {
        f32x4 ov;
#pragma unroll
        for (int i = 0; i < 4; ++i) ov[i] = acc[wi][ntl][mi][i] + bias;
        *(f32x4*)&ob[ro + wi * 8] = ov;
      }
    }
  }
}

extern "C" void kernel_launch(void* const* d_in, const int* in_sizes, int n_in,
                              void* d_out, int out_size, void* d_ws, size_t ws_size,
                              hipStream_t stream) {
  (void)in_sizes; (void)n_in; (void)out_size; (void)ws_size;
  const float* x     = (const float*)d_in[0];
  const float* gamma = (const float*)d_in[1];
  const float* beta  = (const float*)d_in[2];
  const float* wqkv  = (const float*)d_in[3];
  const float* bqkv  = (const float*)d_in[4];
  const float* wout  = (const float*)d_in[5];
  const float* bout  = (const float*)d_in[6];
  float* out = (float*)d_out;

  _Float16* w16   = (_Float16*)d_ws;
  _Float16* xn_ws = (_Float16*)((char*)d_ws + XN_OFF);
  _Float16* o_ws  = (_Float16*)((char*)d_ws + O_OFF);

  static int attr_set = 0;
  if (!attr_set) {
    (void)hipFuncSetAttribute((const void*)prep_kernel,
                              hipFuncAttributeMaxDynamicSharedMemorySize, 149504);
    (void)hipFuncSetAttribute((const void*)megattn_kernel,
                              hipFuncAttributeMaxDynamicSharedMemorySize, 114688);
    (void)hipFuncSetAttribute((const void*)outproj_kernel,
                              hipFuncAttributeMaxDynamicSharedMemorySize, 131072);
    attr_set = 1;
  }

  wcvt_kernel<<<NFRAG / 256, 256, 0, stream>>>(wqkv, wout, w16);
  prep_kernel<<<NQUAD, 512, 149504, stream>>>(x, gamma, beta, xn_ws);
  megattn_kernel<<<NQUAD, 512, 114688, stream>>>(bqkv, w16, xn_ws, o_ws);
  outproj_kernel<<<NQUAD, 512, 131072, stream>>>(o_ws, w16, bout, out);
}

// Round 20
// 410.452 us; speedup vs baseline: 1.9896x; 1.0029x over previous
//
#include <hip/hip_runtime.h>
#include <hip/hip_fp16.h>

#define C_   256
#define H_   224
#define W_   224
#define HW_  (224 * 224)
#define NWH  28
#define NWW  28
#define NWIN 3136
#define NQUAD 784
#define NTILE 64
#define NFRAG (NTILE * 8 * 64)

#define XN_OFF (1ULL << 20)
#define O_OFF  (XN_OFF + (unsigned long long)NWIN * 32768ULL)
#define WS_NEED (O_OFF + (unsigned long long)NWIN * 32768ULL)   // 206.6MB, R5-proven fits

typedef _Float16 f16x8 __attribute__((ext_vector_type(8)));
typedef float    f32x4 __attribute__((ext_vector_type(4)));

// ---- byte-offset swizzles (bijective XOR; 16B-aligned) ----------------------
__device__ __forceinline__ int xn_off(int row, int col) {
  return (row * 512 + col * 2) ^ ((((row & 7) ^ ((row >> 3) & 7))) << 4);
}
__device__ __forceinline__ int qk_off(int row, int col) {
  return (row * 64 + col * 2) ^ (((row >> 1) & 3) << 4);
}
__device__ __forceinline__ int vt_off(int d, int k) {
  return (d * 128 + k * 2) ^ ((d & 7) << 4);
}
__device__ __forceinline__ int p_off(int row, int col) {
  return (row * 128 + col * 2) ^ ((row & 7) << 4);
}
__device__ __forceinline__ _Float16* xn_at(char* s, int r, int c) { return (_Float16*)(s + xn_off(r, c)); }

// ---- weight fp32 -> fragment-major fp16 ------------------------------------
__global__ void wcvt_kernel(const float* __restrict__ wqkv,
                            const float* __restrict__ wout,
                            _Float16* __restrict__ dst) {
  int f = blockIdx.x * blockDim.x + threadIdx.x;
  if (f >= NFRAG) return;
  int lane = f & 63, kk = (f >> 6) & 7, tile = f >> 9;
  int row = tile * 16 + (lane & 15);
  int col = kk * 32 + (lane >> 4) * 8;
  const float* src = (tile < 48) ? (wqkv + row * 256 + col)
                                 : (wout + (row - 768) * 256 + col);
  f32x4 a = *(const f32x4*)src;
  f32x4 b2 = *(const f32x4*)(src + 4);
  f16x8 r;
#pragma unroll
  for (int q = 0; q < 4; ++q) { r[q] = (_Float16)a[q]; r[q + 4] = (_Float16)b2[q]; }
  *(f16x8*)(dst + (size_t)f * 8) = r;
}

// ============================ kernel A: prep (unchanged) =====================
__global__ __launch_bounds__(512, 1) void prep_kernel(
    const float* __restrict__ x, const float* __restrict__ gamma,
    const float* __restrict__ beta, _Float16* __restrict__ xn_ws) {
  extern __shared__ char smem[];
  float* red = (float*)(smem + 131072);
  float* mrs = (float*)(smem + 147456);
  const int n0 = blockIdx.x;
  const int b  = n0 / 196;
  const int rem = n0 % 196;
  const int wh = rem / 7;
  const int wq = rem % 7;
  const int tid = threadIdx.x;
  const int px4 = (tid & 7) * 4;
  const int row = (tid >> 3) & 7;
  const int chg = tid >> 6;
  const int win = px4 >> 3;
  const int pc  = px4 & 7;
  char* xw = smem + win * 32768;

  {
    const size_t xoff = (size_t)b * C_ * HW_ + (size_t)(wh * 8 + row) * W_ + wq * 32 + px4;
    float s[4] = {0.f, 0.f, 0.f, 0.f}, q[4] = {0.f, 0.f, 0.f, 0.f};
#pragma unroll
    for (int cc = 0; cc < 32; ++cc) {
      const int ch = cc * 8 + chg;
      f32x4 v = *(const f32x4*)(x + xoff + (size_t)ch * HW_);
#pragma unroll
      for (int i = 0; i < 4; ++i) {
        *xn_at(xw, row * 8 + pc + i, ch) = (_Float16)v[i];
        s[i] += v[i]; q[i] += v[i] * v[i];
      }
    }
    const int tq = win * 64 + row * 8 + pc;
#pragma unroll
    for (int i = 0; i < 4; ++i) {
      red[(tq + i) * 8 + chg] = s[i];
      red[2048 + (tq + i) * 8 + chg] = q[i];
    }
  }
  __syncthreads();
  if (tid < 256) {
    float ss = 0.f, s2 = 0.f;
#pragma unroll
    for (int g = 0; g < 8; ++g) { ss += red[tid * 8 + g]; s2 += red[2048 + tid * 8 + g]; }
    float mu  = ss * (1.f / 256.f);
    float var = s2 * (1.f / 256.f) - mu * mu;
    mrs[tid]       = mu;
    mrs[256 + tid] = rsqrtf(var + 1e-5f);
  }
  __syncthreads();
  {
    char* dst = (char*)xn_ws + (size_t)((b * NWH + wh) * NWW + wq * 4) * 32768;
#pragma unroll
    for (int it = 0; it < 16; ++it) {
      const int a   = (it * 512 + tid) * 16;
      const int w2  = a >> 15;
      const int ab  = a & 32767;
      const int tok = ab >> 9;
      const int chb = ((ab & 511) ^ ((((tok & 7) ^ ((tok >> 3) & 7))) << 4)) >> 1;
      f16x8 hv = *(const f16x8*)(smem + a);
      const float mu = mrs[w2 * 64 + tok], rs = mrs[256 + w2 * 64 + tok];
      f32x4 g0 = *(const f32x4*)(gamma + chb), g1 = *(const f32x4*)(gamma + chb + 4);
      f32x4 b0 = *(const f32x4*)(beta + chb),  b1 = *(const f32x4*)(beta + chb + 4);
#pragma unroll
      for (int j = 0; j < 4; ++j) {
        hv[j]     = (_Float16)(((float)hv[j] - mu) * rs * g0[j] + b0[j]);
        hv[j + 4] = (_Float16)(((float)hv[j + 4] - mu) * rs * g1[j] + b1[j]);
      }
      *(f16x8*)(dst + a) = hv;
    }
  }
}

// ============================ kernel B: megattn v7 ===========================
// = R14-v3 (proven 238us) with ONE register-neutral edit: p relocated into the
// DEAD q-weight region [0,16384) (head h's weights are dead after GEMM h;
// restaged each head). p becomes wave-private (own rows written+read only)
// -> barrier C2 DELETED; q/k scratch never overwritten mid-head.
// 512 thr = 8 waves; wave w -> window (w>>1), M-half (w&1). LDS 114688 B:
//   [0,49152)       head weights q|k|v (16KB each); [0,16384) doubles as
//                   p [2 win][64][64] fp16 after each head's GEMM
//   [49152,98304)   per-window scratch winl*12288: q 4K | k 4K | vT 4K
//   [98304,114688)  per-window o buffer 4KB
// 3 barriers/head: A (restage safe: all waves done with weights incl. p),
// B (weights staged), C (epilogue q/k/vT visible cross-half).
// VGPR must stay 124 (R15/R17/R18: any extra live state spills at the
// 128-band; launch-bounds min-waves>1 always spills -- R9/R15).
__global__ __launch_bounds__(512, 1) void megattn_kernel(
    const float* __restrict__ bqkv, const _Float16* __restrict__ w16,
    const _Float16* __restrict__ xn_ws, _Float16* __restrict__ o_ws) {
  extern __shared__ char smem[];
  const int tid = threadIdx.x;
  const int w = tid >> 6, lane = tid & 63, lr = lane & 15, lg = lane >> 4;
  const int winl = w >> 1;
  const int half = w & 1;
  const int r0   = half * 32;
  const int win  = blockIdx.x * 4 + winl;

  // A-fragments for this wave's M-half (64 VGPR)
  f16x8 af[2][8];
  {
    const char* xb = (const char*)xn_ws + (size_t)win * 32768;
#pragma unroll
    for (int mi = 0; mi < 2; ++mi)
#pragma unroll
      for (int kk = 0; kk < 8; ++kk)
        af[mi][kk] = *(const f16x8*)(xb + xn_off(r0 + mi * 16 + lr, kk * 32 + lg * 8));
  }

  char* scr   = smem + 49152 + winl * 12288;  // q scratch (stable all head)
  char* kbase = scr + 4096;                   // k scratch
  char* vbase = scr + 8192;                   // vT
  char* pwin  = smem + winl * 8192;           // p in dead q-weight area
  char* obuf  = smem + 98304 + winl * 4096;   // merged o (head-local)
  char* oblob = (char*)o_ws + (size_t)win * 32768;
  const float sc_q = 0.17677669529663687f;    // 1/sqrt(32)

#pragma unroll 1
  for (int h = 0; h < 8; ++h) {
    __syncthreads();   // A: prior head done with weights (incl. p region)
    {
      const char* s0 = (const char*)w16 + (size_t)(2 * h) * 8192;
      const char* s1 = (const char*)w16 + (size_t)(16 + 2 * h) * 8192;
      const char* s2 = (const char*)w16 + (size_t)(32 + 2 * h) * 8192;
#pragma unroll
      for (int it = 0; it < 2; ++it) {
        const int o = (it * 512 + tid) * 16;
        *(f32x4*)(smem + o)         = *(const f32x4*)(s0 + o);
        *(f32x4*)(smem + 16384 + o) = *(const f32x4*)(s1 + o);
        *(f32x4*)(smem + 32768 + o) = *(const f32x4*)(s2 + o);
      }
    }
    __syncthreads();   // B: weights staged

    // ---- GEMM: 6 N-tiles x 2 M-tiles (this wave's half) = 96 MFMA ----
    f32x4 acc[6][2];
#pragma unroll
    for (int t = 0; t < 6; ++t)
#pragma unroll
      for (int mi = 0; mi < 2; ++mi) acc[t][mi] = (f32x4){0.f, 0.f, 0.f, 0.f};
#pragma unroll
    for (int kk = 0; kk < 8; ++kk) {
      const int fo = (kk * 64 + lane) * 16;
      f16x8 b0 = *(const f16x8*)(smem + fo);
      f16x8 b1 = *(const f16x8*)(smem + 8192 + fo);
      f16x8 b2 = *(const f16x8*)(smem + 16384 + fo);
      f16x8 b3 = *(const f16x8*)(smem + 24576 + fo);
      f16x8 b4 = *(const f16x8*)(smem + 32768 + fo);
      f16x8 b5 = *(const f16x8*)(smem + 40960 + fo);
#pragma unroll
      for (int mi = 0; mi < 2; ++mi) {
        acc[0][mi] = __builtin_amdgcn_mfma_f32_16x16x32_f16(af[mi][kk], b0, acc[0][mi], 0, 0, 0);
        acc[1][mi] = __builtin_amdgcn_mfma_f32_16x16x32_f16(af[mi][kk], b1, acc[1][mi], 0, 0, 0);
        acc[2][mi] = __builtin_amdgcn_mfma_f32_16x16x32_f16(af[mi][kk], b2, acc[2][mi], 0, 0, 0);
        acc[3][mi] = __builtin_amdgcn_mfma_f32_16x16x32_f16(af[mi][kk], b3, acc[3][mi], 0, 0, 0);
        acc[4][mi] = __builtin_amdgcn_mfma_f32_16x16x32_f16(af[mi][kk], b4, acc[4][mi], 0, 0, 0);
        acc[5][mi] = __builtin_amdgcn_mfma_f32_16x16x32_f16(af[mi][kk], b5, acc[5][mi], 0, 0, 0);
      }
    }
    // ---- epilogue: q scaled+bias, k bias, vT (this wave's token half) ----
#pragma unroll
    for (int t2 = 0; t2 < 2; ++t2) {
      const float bq = bqkv[h * 32 + t2 * 16 + lr];
      const float bk = bqkv[256 + h * 32 + t2 * 16 + lr];
      const float bv = bqkv[512 + h * 32 + t2 * 16 + lr];
#pragma unroll
      for (int mi = 0; mi < 2; ++mi)
#pragma unroll
        for (int i = 0; i < 4; ++i) {
          const int trow = r0 + mi * 16 + lg * 4 + i;
          *(_Float16*)(scr + qk_off(trow, t2 * 16 + lr))   = (_Float16)((acc[t2][mi][i] + bq) * sc_q);
          *(_Float16*)(kbase + qk_off(trow, t2 * 16 + lr)) = (_Float16)(acc[2 + t2][mi][i] + bk);
          *(_Float16*)(vbase + vt_off(t2 * 16 + lr, trow)) = (_Float16)(acc[4 + t2][mi][i] + bv);
        }
    }
    __syncthreads();   // C: both halves' q/k/vT visible (GEMM also fully done)

    // ---- scores: own q rows x ALL k rows ----
    f16x8 qa[2], kb[4];
#pragma unroll
    for (int mi = 0; mi < 2; ++mi)
      qa[mi] = *(const f16x8*)(scr + qk_off(r0 + mi * 16 + lr, lg * 8));
#pragma unroll
    for (int ni = 0; ni < 4; ++ni)
      kb[ni] = *(const f16x8*)(kbase + qk_off(ni * 16 + lr, lg * 8));

    float oinv[2][4];
#pragma unroll
    for (int mi = 0; mi < 2; ++mi) {
      f32x4 s4[4];
#pragma unroll
      for (int ni = 0; ni < 4; ++ni) {
        f32x4 z = {0.f, 0.f, 0.f, 0.f};
        s4[ni] = __builtin_amdgcn_mfma_f32_16x16x32_f16(qa[mi], kb[ni], z, 0, 0, 0);
      }
#pragma unroll
      for (int i = 0; i < 4; ++i) {
        float m = fmaxf(fmaxf(s4[0][i], s4[1][i]), fmaxf(s4[2][i], s4[3][i]));
        m = fmaxf(m, __shfl_xor(m, 1));
        m = fmaxf(m, __shfl_xor(m, 2));
        m = fmaxf(m, __shfl_xor(m, 4));
        m = fmaxf(m, __shfl_xor(m, 8));
        float s = 0.f;
#pragma unroll
        for (int ni = 0; ni < 4; ++ni) {
          float e = __expf(s4[ni][i] - m);
          s4[ni][i] = e;
          s += e;
        }
        s += __shfl_xor(s, 1);
        s += __shfl_xor(s, 2);
        s += __shfl_xor(s, 4);
        s += __shfl_xor(s, 8);
        oinv[mi][i] = 1.f / s;
      }
      // p -> wave-private rows in dead q-weight region (no barrier needed)
#pragma unroll
      for (int ni = 0; ni < 4; ++ni)
#pragma unroll
        for (int i = 0; i < 4; ++i)
          *(_Float16*)(pwin + p_off(r0 + mi * 16 + lg * 4 + i, ni * 16 + lr)) = (_Float16)s4[ni][i];
    }
    // ---- PV: own p rows x all vT ----
    f32x4 oacc[2][2];
#pragma unroll
    for (int mi = 0; mi < 2; ++mi)
#pragma unroll
      for (int nt2 = 0; nt2 < 2; ++nt2) oacc[mi][nt2] = (f32x4){0.f, 0.f, 0.f, 0.f};
#pragma unroll
    for (int ks2 = 0; ks2 < 2; ++ks2) {
      f16x8 pa[2];
#pragma unroll
      for (int mi = 0; mi < 2; ++mi)
        pa[mi] = *(const f16x8*)(pwin + p_off(r0 + mi * 16 + lr, ks2 * 32 + lg * 8));
#pragma unroll
      for (int nt2 = 0; nt2 < 2; ++nt2) {
        f16x8 vb = *(const f16x8*)(vbase + vt_off(nt2 * 16 + lr, ks2 * 32 + lg * 8));
#pragma unroll
        for (int mi = 0; mi < 2; ++mi)
          oacc[mi][nt2] = __builtin_amdgcn_mfma_f32_16x16x32_f16(pa[mi], vb, oacc[mi][nt2], 0, 0, 0);
      }
    }
    // ---- o-head: assemble own rows in obuf, dump own 2KB half ----
#pragma unroll
    for (int mi = 0; mi < 2; ++mi)
#pragma unroll
      for (int nt2 = 0; nt2 < 2; ++nt2)
#pragma unroll
        for (int i = 0; i < 4; ++i)
          *(_Float16*)(obuf + qk_off(r0 + mi * 16 + lg * 4 + i, nt2 * 16 + lr)) =
              (_Float16)(oacc[mi][nt2][i] * oinv[mi][i]);
#pragma unroll
    for (int j = 0; j < 2; ++j)
      *(f32x4*)(oblob + h * 4096 + half * 2048 + lane * 32 + j * 16) =
          *(const f32x4*)(obuf + half * 2048 + lane * 32 + j * 16);
  }
}

// ============================ kernel C: out-proj (unchanged) =================
__device__ __forceinline__ f16x8 frag16(const _Float16* __restrict__ w16,
                                        int gt, int kk, int lane) {
  return *(const f16x8*)(w16 + ((size_t)((gt * 8 + kk) * 64 + lane)) * 8);
}
__global__ __launch_bounds__(512, 1) void outproj_kernel(
    const _Float16* __restrict__ o_ws, const _Float16* __restrict__ w16,
    const float* __restrict__ bout, float* __restrict__ out) {
  extern __shared__ char smem[];
  const int n0 = blockIdx.x;
  const int b  = n0 / 196;
  const int rem = n0 % 196;
  const int wh = rem / 7;
  const int wq = rem % 7;
  const int tid = threadIdx.x;
  const int w = tid >> 6, lane = tid & 63, lr = lane & 15, lg = lane >> 4;

  {
    const char* src = (const char*)o_ws + (size_t)((b * NWH + wh) * NWW + wq * 4) * 32768;
#pragma unroll
    for (int it = 0; it < 16; ++it) {
      const int off = (it * 512 + tid) * 16;
      *(f32x4*)(smem + off) = *(const f32x4*)(src + off);
    }
  }
  __syncthreads();

  f32x4 acc[4][2][4];
#pragma unroll
  for (int wi = 0; wi < 4; ++wi)
#pragma unroll
    for (int t = 0; t < 2; ++t)
#pragma unroll
      for (int mi = 0; mi < 4; ++mi) acc[wi][t][mi] = (f32x4){0.f, 0.f, 0.f, 0.f};

#pragma unroll
  for (int kk = 0; kk < 8; ++kk) {   // kk == head of the o blob
    f16x8 bf0 = frag16(w16, 48 + w * 2 + 0, kk, lane);
    f16x8 bf1 = frag16(w16, 48 + w * 2 + 1, kk, lane);
#pragma unroll
    for (int wi = 0; wi < 4; ++wi) {
      f16x8 af[4];
#pragma unroll
      for (int mi = 0; mi < 4; ++mi)
        af[mi] = *(const f16x8*)(smem + wi * 32768 + kk * 4096 + qk_off(mi * 16 + lr, lg * 8));
#pragma unroll
      for (int mi = 0; mi < 4; ++mi) {
        acc[wi][0][mi] = __builtin_amdgcn_mfma_f32_16x16x32_f16(af[mi], bf0, acc[wi][0][mi], 0, 0, 0);
        acc[wi][1][mi] = __builtin_amdgcn_mfma_f32_16x16x32_f16(af[mi], bf1, acc[wi][1][mi], 0, 0, 0);
      }
    }
  }

#pragma unroll
  for (int ntl = 0; ntl < 2; ++ntl) {
    const int och = w * 32 + ntl * 16 + lr;
    const float bias = bout[och];
    float* ob = out + ((size_t)(b * C_ + och) * H_ + wh * 8) * W_ + wq * 32;
#pragma unroll
    for (int mi = 0; mi < 4; ++mi) {
      const int tb = mi * 16 + lg * 4;
      const int ro = (tb >> 3) * W_ + (tb & 7);
#pragma unroll
      for (int wi = 0; wi < 4; ++wi) {
        f32x4 ov;
#pragma unroll
        for (int i = 0; i < 4; ++i) ov[i] = acc[wi][ntl][mi][i] + bias;
        *(f32x4*)&ob[ro + wi * 8] = ov;
      }
    }
  }
}

extern "C" void kernel_launch(void* const* d_in, const int* in_sizes, int n_in,
                              void* d_out, int out_size, void* d_ws, size_t ws_size,
                              hipStream_t stream) {
  (void)in_sizes; (void)n_in; (void)out_size; (void)ws_size;
  const float* x     = (const float*)d_in[0];
  const float* gamma = (const float*)d_in[1];
  const float* beta  = (const float*)d_in[2];
  const float* wqkv  = (const float*)d_in[3];
  const float* bqkv  = (const float*)d_in[4];
  const float* wout  = (const float*)d_in[5];
  const float* bout  = (const float*)d_in[6];
  float* out = (float*)d_out;

  _Float16* w16   = (_Float16*)d_ws;
  _Float16* xn_ws = (_Float16*)((char*)d_ws + XN_OFF);
  _Float16* o_ws  = (_Float16*)((char*)d_ws + O_OFF);

  static int attr_set = 0;
  if (!attr_set) {
    (void)hipFuncSetAttribute((const void*)prep_kernel,
                              hipFuncAttributeMaxDynamicSharedMemorySize, 149504);
    (void)hipFuncSetAttribute((const void*)megattn_kernel,
                              hipFuncAttributeMaxDynamicSharedMemorySize, 114688);
    (void)hipFuncSetAttribute((const void*)outproj_kernel,
                              hipFuncAttributeMaxDynamicSharedMemorySize, 131072);
    attr_set = 1;
  }

  wcvt_kernel<<<NFRAG / 256, 256, 0, stream>>>(wqkv, wout, w16);
  prep_kernel<<<NQUAD, 512, 149504, stream>>>(x, gamma, beta, xn_ws);
  megattn_kernel<<<NQUAD, 512, 114688, stream>>>(bqkv, w16, xn_ws, o_ws);
  outproj_kernel<<<NQUAD, 512, 131072, stream>>>(o_ws, w16, bout, out);
}